// Round 5
// baseline (883.244 us; speedup 1.0000x reference)
//
#include <hip/hip_runtime.h>
#include <hip/hip_bf16.h>

#define N_NODES 100000
#define N_EDGES 1600000
#define IN_DIM  500
#define HID     128
#define KDIM    512   // HID * (DEG+1)
#define NB      782   // ceil(N_NODES/128) buckets
#define BCAP    4096  // bucket capacity (expected 2046, >20 sigma headroom)

typedef __attribute__((ext_vector_type(8))) short bf16x8;
typedef __attribute__((ext_vector_type(4))) float f32x4;

__device__ inline short f2bf(float x) {
    union { float f; unsigned u; } v; v.f = x;
    unsigned r = (v.u + 0x7FFFu + ((v.u >> 16) & 1u)) >> 16;  // RNE
    return (short)r;
}
__device__ inline float bf_lo(unsigned u) { union { unsigned u; float f; } v; v.u = u << 16; return v.f; }
__device__ inline float bf_hi(unsigned u) { union { unsigned u; float f; } v; v.u = u & 0xFFFF0000u; return v.f; }
__device__ inline float bf2f(unsigned short s) { union { unsigned u; float f; } v; v.u = ((unsigned)s) << 16; return v.f; }

// ---------------------------------------------------------------------------
// CSR build, two-pass binned (unchanged from R3)
// ---------------------------------------------------------------------------

__global__ __launch_bounds__(256) void bin_kernel(const int* __restrict__ ei,
                                                  int* __restrict__ bcnt,
                                                  unsigned* __restrict__ buf) {
    int e = blockIdx.x * 256 + threadIdx.x;
    if (e < N_EDGES) {
        int r = ei[e];
        int c = ei[N_EDGES + e];
        int b = r >> 7;
        int p = atomicAdd(&bcnt[b * 16], 1);   // stride 64 B: spread L2 slices
        if (p < BCAP) buf[b * BCAP + p] = ((unsigned)(r & 127) << 17) | (unsigned)c;
    }
}

__global__ __launch_bounds__(1024) void bscan_kernel(const int* __restrict__ bcnt,
                                                     int* __restrict__ bbase) {
    __shared__ int buf[1024];
    const int tid = threadIdx.x;
    int v = (tid < NB) ? bcnt[tid * 16] : 0;
    buf[tid] = v;
    __syncthreads();
    for (int off = 1; off < 1024; off <<= 1) {
        int t = (tid >= off) ? buf[tid - off] : 0;
        __syncthreads();
        buf[tid] += t;
        __syncthreads();
    }
    if (tid < NB) bbase[tid] = buf[tid] - v;   // exclusive
}

__global__ __launch_bounds__(256) void place_kernel(const unsigned* __restrict__ buf,
                                                    const int* __restrict__ bcnt,
                                                    const int* __restrict__ bbase,
                                                    int* __restrict__ row_start,
                                                    int* __restrict__ col_sorted) {
    __shared__ int hist[128];
    __shared__ int scan[128];
    __shared__ int cur[128];
    const int b = blockIdx.x, tid = threadIdx.x;
    int cnt = bcnt[b * 16]; if (cnt > BCAP) cnt = BCAP;
    const int base = bbase[b];
    if (tid < 128) hist[tid] = 0;
    __syncthreads();
    for (int i = tid; i < cnt; i += 256)
        atomicAdd(&hist[buf[b * BCAP + i] >> 17], 1);
    __syncthreads();
    if (tid < 128) scan[tid] = hist[tid];
    __syncthreads();
    for (int off = 1; off < 128; off <<= 1) {
        int t = (tid < 128 && tid >= off) ? scan[tid - off] : 0;
        __syncthreads();
        if (tid < 128) scan[tid] += t;
        __syncthreads();
    }
    if (tid < 128) {
        int excl = scan[tid] - hist[tid] + base;
        cur[tid] = excl;
        int r = b * 128 + tid;
        if (r < N_NODES) row_start[r] = excl;
        if (r == N_NODES - 1) row_start[N_NODES] = excl + hist[tid];
    }
    __syncthreads();
    for (int i = tid; i < cnt; i += 256) {
        unsigned u = buf[b * BCAP + i];
        int rl = (int)(u >> 17);
        int c  = (int)(u & 0x1FFFFu);
        int pos = atomicAdd(&cur[rl], 1);
        col_sorted[pos] = c;
    }
}

// ---------------------------------------------------------------------------
// Weight repacks (once per launch): bf16, transposed to [n][k] GEMM-B layout
// ---------------------------------------------------------------------------
__global__ __launch_bounds__(256) void repack_cheb(const float* __restrict__ cheb,
                                                   unsigned short* __restrict__ Bmat) {
    int idx = blockIdx.x * 256 + threadIdx.x;   // < 2*128*512
    int l = idx >> 16;
    int rem = idx & 65535;
    int o = rem >> 9;
    int k = rem & 511;
    int i = k >> 2;
    int d = k & 3;
    Bmat[idx] = (unsigned short)f2bf(cheb[l * 65536 + i * 512 + o * 4 + d]);
}
__global__ __launch_bounds__(256) void repack_w(const float* __restrict__ W,
                                                unsigned short* __restrict__ Wmat) {
    int idx = blockIdx.x * 256 + threadIdx.x;   // < 128*512
    int o = idx >> 9;
    int k = idx & 511;
    Wmat[idx] = (k < IN_DIM) ? (unsigned short)f2bf(W[k * HID + o]) : 0;
}

// ---------------------------------------------------------------------------
// MFMA GEMM 1: h = x @ W_in  [100000 x 500] @ [500 x 128] -> bf16
// Barrier-free, LDS-free: A-frags loaded f32 direct from x (32 B/lane/frag),
// B-frags 16 B direct from L2-hot prepacked Wmat[n][k]. Waves independent.
// ---------------------------------------------------------------------------
__global__ __launch_bounds__(256, 2) void gemm_xw(const float* __restrict__ x,
                                                  const unsigned short* __restrict__ Wmat,
                                                  unsigned short* __restrict__ out) {
    const int tid  = threadIdx.x;
    const int lane = tid & 63;
    const int wave = tid >> 6;
    const int quad = lane >> 4;
    const int l16  = lane & 15;
    const int n0   = blockIdx.x * 128;

    int row0 = n0 + wave * 32 + l16;      if (row0 >= N_NODES) row0 = N_NODES - 1;
    int row1 = n0 + wave * 32 + 16 + l16; if (row1 >= N_NODES) row1 = N_NODES - 1;
    const float* __restrict__ xr0 = x + (long)row0 * IN_DIM + quad * 8;
    const float* __restrict__ xr1 = x + (long)row1 * IN_DIM + quad * 8;

    f32x4 acc[2][8];
#pragma unroll
    for (int mt = 0; mt < 2; mt++)
#pragma unroll
        for (int nt = 0; nt < 8; nt++)
#pragma unroll
            for (int r = 0; r < 4; r++) acc[mt][nt][r] = 0.f;

#pragma unroll 2
    for (int kt = 0; kt < 15; kt++) {      // k0 = 0..448: quad*8+8 <= 480 < 500, safe
        const int k0 = kt * 32;
        float4 f0a = *(const float4*)(xr0 + k0);
        float4 f0b = *(const float4*)(xr0 + k0 + 4);
        float4 f1a = *(const float4*)(xr1 + k0);
        float4 f1b = *(const float4*)(xr1 + k0 + 4);
        short t0[8] = {f2bf(f0a.x), f2bf(f0a.y), f2bf(f0a.z), f2bf(f0a.w),
                       f2bf(f0b.x), f2bf(f0b.y), f2bf(f0b.z), f2bf(f0b.w)};
        short t1[8] = {f2bf(f1a.x), f2bf(f1a.y), f2bf(f1a.z), f2bf(f1a.w),
                       f2bf(f1b.x), f2bf(f1b.y), f2bf(f1b.z), f2bf(f1b.w)};
        bf16x8 a0 = *(bf16x8*)t0;
        bf16x8 a1 = *(bf16x8*)t1;
#pragma unroll
        for (int nt = 0; nt < 8; nt++) {
            bf16x8 b = *(const bf16x8*)&Wmat[(nt * 16 + l16) * 512 + k0 + quad * 8];
            acc[0][nt] = __builtin_amdgcn_mfma_f32_16x16x32_bf16(a0, b, acc[0][nt], 0, 0, 0);
            acc[1][nt] = __builtin_amdgcn_mfma_f32_16x16x32_bf16(a1, b, acc[1][nt], 0, 0, 0);
        }
    }
    {   // tail k-tile, k0 = 480: guard elements >= IN_DIM
        const int k0 = 480;
        short t0[8], t1[8];
#pragma unroll
        for (int q = 0; q < 8; q++) {
            int kk = k0 + quad * 8 + q;
            t0[q] = (kk < IN_DIM) ? f2bf(xr0[k0 + q]) : (short)0;
            t1[q] = (kk < IN_DIM) ? f2bf(xr1[k0 + q]) : (short)0;
        }
        bf16x8 a0 = *(bf16x8*)t0;
        bf16x8 a1 = *(bf16x8*)t1;
#pragma unroll
        for (int nt = 0; nt < 8; nt++) {
            bf16x8 b = *(const bf16x8*)&Wmat[(nt * 16 + l16) * 512 + k0 + quad * 8];
            acc[0][nt] = __builtin_amdgcn_mfma_f32_16x16x32_bf16(a0, b, acc[0][nt], 0, 0, 0);
            acc[1][nt] = __builtin_amdgcn_mfma_f32_16x16x32_bf16(a1, b, acc[1][nt], 0, 0, 0);
        }
    }
#pragma unroll
    for (int mt = 0; mt < 2; mt++) {
        int mrow = n0 + wave * 32 + mt * 16 + quad * 4;
#pragma unroll
        for (int r = 0; r < 4; r++) {
            int n = mrow + r;
            if (n < N_NODES) {
#pragma unroll
                for (int nt = 0; nt < 8; nt++)
                    out[(long)n * HID + nt * 16 + l16] = (unsigned short)f2bf(acc[mt][nt][r]);
            }
        }
    }
}

// ---------------------------------------------------------------------------
// MFMA GEMM 2: out = Basis(h) @ C  [N x 512]@[512 x 128]
// Barrier-free, LDS-free: per k-frag each lane reads 2 bf16 h-features (4 B),
// computes tanh/Chebyshev basis in-register; B-frags direct from L2-hot Bmat.
// ---------------------------------------------------------------------------
__global__ __launch_bounds__(256, 2) void cheb_gemm(const unsigned short* __restrict__ h,
                                                    const unsigned short* __restrict__ Bmat,
                                                    unsigned short* __restrict__ out) {
    const int tid  = threadIdx.x;
    const int lane = tid & 63;
    const int wave = tid >> 6;
    const int quad = lane >> 4;
    const int l16  = lane & 15;
    const int n0   = blockIdx.x * 128;

    int row0 = n0 + wave * 32 + l16;      if (row0 >= N_NODES) row0 = N_NODES - 1;
    int row1 = n0 + wave * 32 + 16 + l16; if (row1 >= N_NODES) row1 = N_NODES - 1;
    const unsigned* __restrict__ hr0 = (const unsigned*)(h + (long)row0 * HID) + quad;
    const unsigned* __restrict__ hr1 = (const unsigned*)(h + (long)row1 * HID) + quad;

    f32x4 acc[2][8];
#pragma unroll
    for (int mt = 0; mt < 2; mt++)
#pragma unroll
        for (int nt = 0; nt < 8; nt++)
#pragma unroll
            for (int r = 0; r < 4; r++) acc[mt][nt][r] = 0.f;

#pragma unroll 2
    for (int kt = 0; kt < 16; kt++) {
        const int k0 = kt * 32;
        // lane covers features i0 = kt*8 + quad*2 and i0+1 (one uint each row)
        unsigned u0 = hr0[kt * 4];
        unsigned u1 = hr1[kt * 4];
        short t0[8], t1[8];
        {
            float hx[2] = {bf_lo(u0), bf_hi(u0)};
#pragma unroll
            for (int q = 0; q < 2; q++) {
                float xx = fminf(fmaxf(hx[q], -15.f), 15.f);
                float e  = __expf(2.f * xx);
                float t  = (e - 1.f) / (e + 1.f);
                float T2 = 2.f * t * t - 1.f;
                float T3 = 2.f * t * T2 - t;
                t0[q * 4 + 0] = (short)0x3F80;
                t0[q * 4 + 1] = f2bf(t);
                t0[q * 4 + 2] = f2bf(T2);
                t0[q * 4 + 3] = f2bf(T3);
            }
        }
        {
            float hx[2] = {bf_lo(u1), bf_hi(u1)};
#pragma unroll
            for (int q = 0; q < 2; q++) {
                float xx = fminf(fmaxf(hx[q], -15.f), 15.f);
                float e  = __expf(2.f * xx);
                float t  = (e - 1.f) / (e + 1.f);
                float T2 = 2.f * t * t - 1.f;
                float T3 = 2.f * t * T2 - t;
                t1[q * 4 + 0] = (short)0x3F80;
                t1[q * 4 + 1] = f2bf(t);
                t1[q * 4 + 2] = f2bf(T2);
                t1[q * 4 + 3] = f2bf(T3);
            }
        }
        bf16x8 a0 = *(bf16x8*)t0;
        bf16x8 a1 = *(bf16x8*)t1;
#pragma unroll
        for (int nt = 0; nt < 8; nt++) {
            bf16x8 b = *(const bf16x8*)&Bmat[(nt * 16 + l16) * 512 + k0 + quad * 8];
            acc[0][nt] = __builtin_amdgcn_mfma_f32_16x16x32_bf16(a0, b, acc[0][nt], 0, 0, 0);
            acc[1][nt] = __builtin_amdgcn_mfma_f32_16x16x32_bf16(a1, b, acc[1][nt], 0, 0, 0);
        }
    }
#pragma unroll
    for (int mt = 0; mt < 2; mt++) {
        int mrow = n0 + wave * 32 + mt * 16 + quad * 4;
#pragma unroll
        for (int r = 0; r < 4; r++) {
            int n = mrow + r;
            if (n < N_NODES) {
#pragma unroll
                for (int nt = 0; nt < 8; nt++)
                    out[(long)n * HID + nt * 16 + l16] = (unsigned short)f2bf(acc[mt][nt][r]);
            }
        }
    }
}

// ---------------------------------------------------------------------------
// SpMM gather (bf16): wave/row, uint (2xbf16)/lane, 4-edge unroll for ILP
// ---------------------------------------------------------------------------
__global__ __launch_bounds__(256) void spmm_gather(const int* __restrict__ row_start,
                                                   const int* __restrict__ col_sorted,
                                                   const unsigned short* __restrict__ h,
                                                   unsigned short* __restrict__ out) {
    const int wid  = (blockIdx.x * 256 + threadIdx.x) >> 6;
    const int lane = threadIdx.x & 63;
    if (wid >= N_NODES) return;
    const int s = row_start[wid];
    const int e = row_start[wid + 1];
    const unsigned* __restrict__ h1 = (const unsigned*)h;
    float ax0 = 0.f, ay0 = 0.f, ax1 = 0.f, ay1 = 0.f;
    float ax2 = 0.f, ay2 = 0.f, ax3 = 0.f, ay3 = 0.f;
    int j = s;
    for (; j + 3 < e; j += 4) {
        int c0 = col_sorted[j];
        int c1 = col_sorted[j + 1];
        int c2 = col_sorted[j + 2];
        int c3 = col_sorted[j + 3];
        unsigned u0 = h1[c0 * 64 + lane];
        unsigned u1 = h1[c1 * 64 + lane];
        unsigned u2 = h1[c2 * 64 + lane];
        unsigned u3 = h1[c3 * 64 + lane];
        ax0 += bf_lo(u0); ay0 += bf_hi(u0);
        ax1 += bf_lo(u1); ay1 += bf_hi(u1);
        ax2 += bf_lo(u2); ay2 += bf_hi(u2);
        ax3 += bf_lo(u3); ay3 += bf_hi(u3);
    }
    for (; j < e; j++) {
        unsigned u = h1[col_sorted[j] * 64 + lane];
        ax0 += bf_lo(u); ay0 += bf_hi(u);
    }
    ax0 += ax1 + ax2 + ax3; ay0 += ay1 + ay2 + ay3;
    unsigned lo = (unsigned)(unsigned short)f2bf(ax0);
    unsigned hi = (unsigned)(unsigned short)f2bf(ay0);
    ((unsigned*)out)[wid * 64 + lane] = lo | (hi << 16);
}

// ---------------------------------------------------------------------------
// Output GEMM (128->16) + log_softmax, fused. h bf16 in, f32 out.
// ---------------------------------------------------------------------------
__global__ __launch_bounds__(256) void out_kernel(const unsigned short* __restrict__ h,
                                                  const float* __restrict__ Wo,
                                                  float* __restrict__ out) {
    __shared__ float Ws[HID * 16];
    __shared__ float Hs[16][HID];
    const int tid = threadIdx.x;
    const int n0 = blockIdx.x * 16;
    for (int idx = tid; idx < HID * 16; idx += 256) Ws[idx] = Wo[idx];
    const unsigned* h1 = (const unsigned*)h;
    for (int idx = tid; idx < 16 * 64; idx += 256) {
        int nl = idx >> 6;
        int kp = idx & 63;
        unsigned u = h1[(n0 + nl) * 64 + kp];
        Hs[nl][kp * 2]     = bf_lo(u);
        Hs[nl][kp * 2 + 1] = bf_hi(u);
    }
    __syncthreads();
    const int nl = tid >> 4;
    const int o  = tid & 15;
    float acc = 0.f;
#pragma unroll
    for (int k = 0; k < HID; k++) acc += Hs[nl][k] * Ws[k * 16 + o];
    float mx = acc;
#pragma unroll
    for (int m = 8; m >= 1; m >>= 1) mx = fmaxf(mx, __shfl_xor(mx, m));
    float ex = expf(acc - mx);
    float se = ex;
#pragma unroll
    for (int m = 8; m >= 1; m >>= 1) se += __shfl_xor(se, m);
    out[(n0 + nl) * 16 + o] = acc - mx - logf(se);
}

// ---------------------------------------------------------------------------

extern "C" void kernel_launch(void* const* d_in, const int* in_sizes, int n_in,
                              void* d_out, int out_size, void* d_ws, size_t ws_size,
                              hipStream_t stream) {
    const float* x     = (const float*)d_in[0];
    const int*   ei    = (const int*)d_in[1];
    const float* W_in  = (const float*)d_in[2];
    const float* cheb  = (const float*)d_in[3];
    const float* W_out = (const float*)d_in[4];
    float* out = (float*)d_out;

    char* p = (char*)d_ws;
    unsigned short* hA   = (unsigned short*)p; p += (size_t)N_NODES * HID * 2;   // 25.6 MB
    unsigned short* hB   = (unsigned short*)p; p += (size_t)N_NODES * HID * 2;   // 25.6 MB
    int*   col_sorted    = (int*)p;            p += (size_t)N_EDGES * 4;         // 6.4 MB
    unsigned short* Bmat = (unsigned short*)p; p += (size_t)2 * HID * KDIM * 2;  // 256 KB
    unsigned short* Wmat = (unsigned short*)p; p += (size_t)HID * KDIM * 2;      // 128 KB
    int*   row_start     = (int*)p;            p += (size_t)(N_NODES + 1) * 4;
    int*   bcnt          = (int*)p;            p += (size_t)NB * 16 * 4;         // 50 KB
    int*   bbase         = (int*)p;            p += (size_t)NB * 4;

    // bucket buffer aliases hA (dead until gemm_xw): 782*4096*4 = 12.8 MB < 25.6 MB
    unsigned* bbuf = (unsigned*)hA;

    const int nblk_gemm = (N_NODES + 127) / 128;       // 782
    const int nblk_edge = N_EDGES / 256;               // 6250
    const int nblk_spmm = (N_NODES + 3) / 4;           // 25000
    const int nblk_out  = N_NODES / 16;                // 6250

    hipMemsetAsync(bcnt, 0, (size_t)NB * 16 * 4, stream);
    bin_kernel<<<nblk_edge, 256, 0, stream>>>(ei, bcnt, bbuf);
    bscan_kernel<<<1, 1024, 0, stream>>>(bcnt, bbase);
    place_kernel<<<NB, 256, 0, stream>>>(bbuf, bcnt, bbase, row_start, col_sorted);
    repack_cheb<<<2 * HID * KDIM / 256, 256, 0, stream>>>(cheb, Bmat);
    repack_w<<<HID * KDIM / 256, 256, 0, stream>>>(W_in, Wmat);

    gemm_xw<<<nblk_gemm, 256, 0, stream>>>(x, Wmat, hA);
    spmm_gather<<<nblk_spmm, 256, 0, stream>>>(row_start, col_sorted, hA, hB);

    cheb_gemm<<<nblk_gemm, 256, 0, stream>>>(hB, Bmat, hA);                    // layer 0
    spmm_gather<<<nblk_spmm, 256, 0, stream>>>(row_start, col_sorted, hA, hB);

    cheb_gemm<<<nblk_gemm, 256, 0, stream>>>(hB, Bmat + HID * KDIM, hA);       // layer 1
    spmm_gather<<<nblk_spmm, 256, 0, stream>>>(row_start, col_sorted, hA, hB);

    out_kernel<<<nblk_out, 256, 0, stream>>>(hB, W_out, out);
}

// Round 6
// 721.790 us; speedup vs baseline: 1.2237x; 1.2237x over previous
//
#include <hip/hip_runtime.h>
#include <hip/hip_bf16.h>

#define N_NODES 100000
#define N_EDGES 1600000
#define IN_DIM  500
#define HID     128
#define KDIM    512   // HID * (DEG+1)
#define NB      782   // ceil(N_NODES/128) buckets
#define BCAP    4096  // bucket capacity (expected 2046, >20 sigma headroom)

typedef __attribute__((ext_vector_type(8))) short bf16x8;
typedef __attribute__((ext_vector_type(4))) float f32x4;

__device__ inline short f2bf(float x) {
    union { float f; unsigned u; } v; v.f = x;
    unsigned r = (v.u + 0x7FFFu + ((v.u >> 16) & 1u)) >> 16;  // RNE
    return (short)r;
}
__device__ inline float bf_lo(unsigned u) { union { unsigned u; float f; } v; v.u = u << 16; return v.f; }
__device__ inline float bf_hi(unsigned u) { union { unsigned u; float f; } v; v.u = u & 0xFFFF0000u; return v.f; }
__device__ inline float bf2f(unsigned short s) { union { unsigned u; float f; } v; v.u = ((unsigned)s) << 16; return v.f; }

// ---------------------------------------------------------------------------
// CSR build, two-pass binned (unchanged from R3)
// ---------------------------------------------------------------------------

__global__ __launch_bounds__(256) void bin_kernel(const int* __restrict__ ei,
                                                  int* __restrict__ bcnt,
                                                  unsigned* __restrict__ buf) {
    int e = blockIdx.x * 256 + threadIdx.x;
    if (e < N_EDGES) {
        int r = ei[e];
        int c = ei[N_EDGES + e];
        int b = r >> 7;
        int p = atomicAdd(&bcnt[b * 16], 1);   // stride 64 B: spread L2 slices
        if (p < BCAP) buf[b * BCAP + p] = ((unsigned)(r & 127) << 17) | (unsigned)c;
    }
}

__global__ __launch_bounds__(1024) void bscan_kernel(const int* __restrict__ bcnt,
                                                     int* __restrict__ bbase) {
    __shared__ int buf[1024];
    const int tid = threadIdx.x;
    int v = (tid < NB) ? bcnt[tid * 16] : 0;
    buf[tid] = v;
    __syncthreads();
    for (int off = 1; off < 1024; off <<= 1) {
        int t = (tid >= off) ? buf[tid - off] : 0;
        __syncthreads();
        buf[tid] += t;
        __syncthreads();
    }
    if (tid < NB) bbase[tid] = buf[tid] - v;   // exclusive
}

__global__ __launch_bounds__(256) void place_kernel(const unsigned* __restrict__ buf,
                                                    const int* __restrict__ bcnt,
                                                    const int* __restrict__ bbase,
                                                    int* __restrict__ row_start,
                                                    int* __restrict__ col_sorted) {
    __shared__ int hist[128];
    __shared__ int scan[128];
    __shared__ int cur[128];
    const int b = blockIdx.x, tid = threadIdx.x;
    int cnt = bcnt[b * 16]; if (cnt > BCAP) cnt = BCAP;
    const int base = bbase[b];
    if (tid < 128) hist[tid] = 0;
    __syncthreads();
    for (int i = tid; i < cnt; i += 256)
        atomicAdd(&hist[buf[b * BCAP + i] >> 17], 1);
    __syncthreads();
    if (tid < 128) scan[tid] = hist[tid];
    __syncthreads();
    for (int off = 1; off < 128; off <<= 1) {
        int t = (tid < 128 && tid >= off) ? scan[tid - off] : 0;
        __syncthreads();
        if (tid < 128) scan[tid] += t;
        __syncthreads();
    }
    if (tid < 128) {
        int excl = scan[tid] - hist[tid] + base;
        cur[tid] = excl;
        int r = b * 128 + tid;
        if (r < N_NODES) row_start[r] = excl;
        if (r == N_NODES - 1) row_start[N_NODES] = excl + hist[tid];
    }
    __syncthreads();
    for (int i = tid; i < cnt; i += 256) {
        unsigned u = buf[b * BCAP + i];
        int rl = (int)(u >> 17);
        int c  = (int)(u & 0x1FFFFu);
        int pos = atomicAdd(&cur[rl], 1);
        col_sorted[pos] = c;
    }
}

// ---------------------------------------------------------------------------
// Weight repacks (once per launch): bf16, transposed to [n][k] GEMM-B layout
// ---------------------------------------------------------------------------
__global__ __launch_bounds__(256) void repack_cheb(const float* __restrict__ cheb,
                                                   unsigned short* __restrict__ Bmat) {
    int idx = blockIdx.x * 256 + threadIdx.x;   // < 2*128*512
    int l = idx >> 16;
    int rem = idx & 65535;
    int o = rem >> 9;
    int k = rem & 511;
    int i = k >> 2;
    int d = k & 3;
    Bmat[idx] = (unsigned short)f2bf(cheb[l * 65536 + i * 512 + o * 4 + d]);
}
__global__ __launch_bounds__(256) void repack_w(const float* __restrict__ W,
                                                unsigned short* __restrict__ Wmat) {
    int idx = blockIdx.x * 256 + threadIdx.x;   // < 128*512
    int o = idx >> 9;
    int k = idx & 511;
    Wmat[idx] = (k < IN_DIM) ? (unsigned short)f2bf(W[k * HID + o]) : 0;
}

// ---------------------------------------------------------------------------
// MFMA GEMM 1: h = x @ W_in  [100000 x 500(512)] @ [500 x 128] -> bf16
// LDS-staged (coalesced global loads), double-buffered LDS + register
// prefetch, 1 barrier per K-tile. 128x128 tile, BK=32, 4 waves/block.
// ---------------------------------------------------------------------------
__global__ __launch_bounds__(256, 3) void gemm_xw(const float* __restrict__ x,
                                                  const unsigned short* __restrict__ Wmat,
                                                  unsigned short* __restrict__ out) {
    __shared__ __align__(16) short As[2][128][40];   // [buf][m][k], row 80 B
    __shared__ __align__(16) short Bs[2][128][40];
    const int tid  = threadIdx.x;
    const int lane = tid & 63;
    const int wave = tid >> 6;
    const int quad = lane >> 4;
    const int l16  = lane & 15;
    const int n0   = blockIdx.x * 128;
    const int lr   = tid >> 1;     // A-stage row 0..127
    const int lh   = tid & 1;      // A-stage k-half (16 floats each)
    const int bm   = tid >> 2;     // B-stage row 0..63 (and +64)
    const int bkq  = tid & 3;      // B-stage k-quad

    int nA = n0 + lr; if (nA >= N_NODES) nA = N_NODES - 1;
    const float* __restrict__ xrow = x + (long)nA * IN_DIM;

    f32x4 acc[2][8];
#pragma unroll
    for (int mt = 0; mt < 2; mt++)
#pragma unroll
        for (int nt = 0; nt < 8; nt++)
#pragma unroll
            for (int r = 0; r < 4; r++) acc[mt][nt][r] = 0.f;

    auto loadA = [&](int kt, float (&v)[16]) {
        const int kb = kt * 32 + lh * 16;
        if (kb + 16 <= IN_DIM) {
            const float4* s4 = (const float4*)(xrow + kb);
            float4 a0 = s4[0], a1 = s4[1], a2 = s4[2], a3 = s4[3];
            v[0]=a0.x; v[1]=a0.y; v[2]=a0.z; v[3]=a0.w;
            v[4]=a1.x; v[5]=a1.y; v[6]=a1.z; v[7]=a1.w;
            v[8]=a2.x; v[9]=a2.y; v[10]=a2.z; v[11]=a2.w;
            v[12]=a3.x; v[13]=a3.y; v[14]=a3.z; v[15]=a3.w;
        } else {
#pragma unroll
            for (int q = 0; q < 16; q++) v[q] = (kb + q < IN_DIM) ? xrow[kb + q] : 0.f;
        }
    };
    auto loadB = [&](int kt, bf16x8 (&w)[2]) {
        w[0] = *(const bf16x8*)&Wmat[bm * 512 + kt * 32 + bkq * 8];
        w[1] = *(const bf16x8*)&Wmat[(bm + 64) * 512 + kt * 32 + bkq * 8];
    };
    auto storeA = [&](int buf, const float (&v)[16]) {
        short t[16];
#pragma unroll
        for (int q = 0; q < 16; q++) t[q] = f2bf(v[q]);
        *(bf16x8*)&As[buf][lr][lh * 16]     = *(bf16x8*)&t[0];
        *(bf16x8*)&As[buf][lr][lh * 16 + 8] = *(bf16x8*)&t[8];
    };
    auto storeB = [&](int buf, const bf16x8 (&w)[2]) {
        *(bf16x8*)&Bs[buf][bm][bkq * 8]      = w[0];
        *(bf16x8*)&Bs[buf][bm + 64][bkq * 8] = w[1];
    };
    auto mfmaTile = [&](int buf) {
        bf16x8 a0 = *(const bf16x8*)&As[buf][wave * 32 + l16][quad * 8];
        bf16x8 a1 = *(const bf16x8*)&As[buf][wave * 32 + 16 + l16][quad * 8];
#pragma unroll
        for (int nt = 0; nt < 8; nt++) {
            bf16x8 b = *(const bf16x8*)&Bs[buf][nt * 16 + l16][quad * 8];
            acc[0][nt] = __builtin_amdgcn_mfma_f32_16x16x32_bf16(a0, b, acc[0][nt], 0, 0, 0);
            acc[1][nt] = __builtin_amdgcn_mfma_f32_16x16x32_bf16(a1, b, acc[1][nt], 0, 0, 0);
        }
    };

    float  va[16], vb[16];
    bf16x8 wa[2],  wb[2];
    loadA(0, va); loadB(0, wa);
    for (int kt = 0; kt < 16; kt += 2) {
        storeA(0, va); storeB(0, wa);
        loadA(kt + 1, vb); loadB(kt + 1, wb);     // prefetch odd tile
        __syncthreads();
        mfmaTile(0);
        storeA(1, vb); storeB(1, wb);
        if (kt + 2 < 16) { loadA(kt + 2, va); loadB(kt + 2, wa); }  // prefetch next even
        __syncthreads();
        mfmaTile(1);
    }

#pragma unroll
    for (int mt = 0; mt < 2; mt++) {
        int mrow = n0 + wave * 32 + mt * 16 + quad * 4;
#pragma unroll
        for (int r = 0; r < 4; r++) {
            int n = mrow + r;
            if (n < N_NODES) {
#pragma unroll
                for (int nt = 0; nt < 8; nt++)
                    out[(long)n * HID + nt * 16 + l16] = (unsigned short)f2bf(acc[mt][nt][r]);
            }
        }
    }
}

// ---------------------------------------------------------------------------
// MFMA GEMM 2: out = Basis(h) @ C  [N x 512]@[512 x 128], basis on the fly.
// Same dbuf + register-prefetch structure; tanh/Chebyshev done at store time.
// ---------------------------------------------------------------------------
__global__ __launch_bounds__(256, 3) void cheb_gemm(const unsigned short* __restrict__ h,
                                                    const unsigned short* __restrict__ Bmat,
                                                    unsigned short* __restrict__ out) {
    __shared__ __align__(16) short As[2][128][40];
    __shared__ __align__(16) short Bs[2][128][40];
    const int tid  = threadIdx.x;
    const int lane = tid & 63;
    const int wave = tid >> 6;
    const int quad = lane >> 4;
    const int l16  = lane & 15;
    const int n0   = blockIdx.x * 128;
    const int lr   = tid >> 1;
    const int lh   = tid & 1;
    const int bm   = tid >> 2;
    const int bkq  = tid & 3;

    int nA = n0 + lr; if (nA >= N_NODES) nA = N_NODES - 1;
    const unsigned short* __restrict__ hrow = h + (long)nA * HID;

    f32x4 acc[2][8];
#pragma unroll
    for (int mt = 0; mt < 2; mt++)
#pragma unroll
        for (int nt = 0; nt < 8; nt++)
#pragma unroll
            for (int r = 0; r < 4; r++) acc[mt][nt][r] = 0.f;

    auto loadA = [&](int kt, ushort4& v) {
        v = *(const ushort4*)(hrow + kt * 8 + lh * 4);   // 4 h-features
    };
    auto loadB = [&](int kt, bf16x8 (&w)[2]) {
        w[0] = *(const bf16x8*)&Bmat[bm * 512 + kt * 32 + bkq * 8];
        w[1] = *(const bf16x8*)&Bmat[(bm + 64) * 512 + kt * 32 + bkq * 8];
    };
    auto storeA = [&](int buf, const ushort4& v) {
        float hx[4] = {bf2f(v.x), bf2f(v.y), bf2f(v.z), bf2f(v.w)};
        short t[16];
#pragma unroll
        for (int q = 0; q < 4; q++) {
            float xx = fminf(fmaxf(hx[q], -15.f), 15.f);
            float e  = __expf(2.f * xx);
            float tt = (e - 1.f) / (e + 1.f);     // tanh
            float T2 = 2.f * tt * tt - 1.f;
            float T3 = 2.f * tt * T2 - tt;
            t[q * 4 + 0] = (short)0x3F80;         // bf16(1.0)
            t[q * 4 + 1] = f2bf(tt);
            t[q * 4 + 2] = f2bf(T2);
            t[q * 4 + 3] = f2bf(T3);
        }
        *(bf16x8*)&As[buf][lr][lh * 16]     = *(bf16x8*)&t[0];
        *(bf16x8*)&As[buf][lr][lh * 16 + 8] = *(bf16x8*)&t[8];
    };
    auto storeB = [&](int buf, const bf16x8 (&w)[2]) {
        *(bf16x8*)&Bs[buf][bm][bkq * 8]      = w[0];
        *(bf16x8*)&Bs[buf][bm + 64][bkq * 8] = w[1];
    };
    auto mfmaTile = [&](int buf) {
        bf16x8 a0 = *(const bf16x8*)&As[buf][wave * 32 + l16][quad * 8];
        bf16x8 a1 = *(const bf16x8*)&As[buf][wave * 32 + 16 + l16][quad * 8];
#pragma unroll
        for (int nt = 0; nt < 8; nt++) {
            bf16x8 b = *(const bf16x8*)&Bs[buf][nt * 16 + l16][quad * 8];
            acc[0][nt] = __builtin_amdgcn_mfma_f32_16x16x32_bf16(a0, b, acc[0][nt], 0, 0, 0);
            acc[1][nt] = __builtin_amdgcn_mfma_f32_16x16x32_bf16(a1, b, acc[1][nt], 0, 0, 0);
        }
    };

    ushort4 va, vb;
    bf16x8  wa[2], wb[2];
    loadA(0, va); loadB(0, wa);
    for (int kt = 0; kt < 16; kt += 2) {
        storeA(0, va); storeB(0, wa);
        loadA(kt + 1, vb); loadB(kt + 1, wb);
        __syncthreads();
        mfmaTile(0);
        storeA(1, vb); storeB(1, wb);
        if (kt + 2 < 16) { loadA(kt + 2, va); loadB(kt + 2, wa); }
        __syncthreads();
        mfmaTile(1);
    }

#pragma unroll
    for (int mt = 0; mt < 2; mt++) {
        int mrow = n0 + wave * 32 + mt * 16 + quad * 4;
#pragma unroll
        for (int r = 0; r < 4; r++) {
            int n = mrow + r;
            if (n < N_NODES) {
#pragma unroll
                for (int nt = 0; nt < 8; nt++)
                    out[(long)n * HID + nt * 16 + l16] = (unsigned short)f2bf(acc[mt][nt][r]);
            }
        }
    }
}

// ---------------------------------------------------------------------------
// SpMM gather (bf16): wave/row, uint (2xbf16)/lane, 4-edge unroll for ILP
// ---------------------------------------------------------------------------
__global__ __launch_bounds__(256) void spmm_gather(const int* __restrict__ row_start,
                                                   const int* __restrict__ col_sorted,
                                                   const unsigned short* __restrict__ h,
                                                   unsigned short* __restrict__ out) {
    const int wid  = (blockIdx.x * 256 + threadIdx.x) >> 6;
    const int lane = threadIdx.x & 63;
    if (wid >= N_NODES) return;
    const int s = row_start[wid];
    const int e = row_start[wid + 1];
    const unsigned* __restrict__ h1 = (const unsigned*)h;
    float ax0 = 0.f, ay0 = 0.f, ax1 = 0.f, ay1 = 0.f;
    float ax2 = 0.f, ay2 = 0.f, ax3 = 0.f, ay3 = 0.f;
    int j = s;
    for (; j + 3 < e; j += 4) {
        int c0 = col_sorted[j];
        int c1 = col_sorted[j + 1];
        int c2 = col_sorted[j + 2];
        int c3 = col_sorted[j + 3];
        unsigned u0 = h1[c0 * 64 + lane];
        unsigned u1 = h1[c1 * 64 + lane];
        unsigned u2 = h1[c2 * 64 + lane];
        unsigned u3 = h1[c3 * 64 + lane];
        ax0 += bf_lo(u0); ay0 += bf_hi(u0);
        ax1 += bf_lo(u1); ay1 += bf_hi(u1);
        ax2 += bf_lo(u2); ay2 += bf_hi(u2);
        ax3 += bf_lo(u3); ay3 += bf_hi(u3);
    }
    for (; j < e; j++) {
        unsigned u = h1[col_sorted[j] * 64 + lane];
        ax0 += bf_lo(u); ay0 += bf_hi(u);
    }
    ax0 += ax1 + ax2 + ax3; ay0 += ay1 + ay2 + ay3;
    unsigned lo = (unsigned)(unsigned short)f2bf(ax0);
    unsigned hi = (unsigned)(unsigned short)f2bf(ay0);
    ((unsigned*)out)[wid * 64 + lane] = lo | (hi << 16);
}

// ---------------------------------------------------------------------------
// Output GEMM (128->16) + log_softmax, fused. h bf16 in, f32 out.
// ---------------------------------------------------------------------------
__global__ __launch_bounds__(256) void out_kernel(const unsigned short* __restrict__ h,
                                                  const float* __restrict__ Wo,
                                                  float* __restrict__ out) {
    __shared__ float Ws[HID * 16];
    __shared__ float Hs[16][HID];
    const int tid = threadIdx.x;
    const int n0 = blockIdx.x * 16;
    for (int idx = tid; idx < HID * 16; idx += 256) Ws[idx] = Wo[idx];
    const unsigned* h1 = (const unsigned*)h;
    for (int idx = tid; idx < 16 * 64; idx += 256) {
        int nl = idx >> 6;
        int kp = idx & 63;
        unsigned u = h1[(n0 + nl) * 64 + kp];
        Hs[nl][kp * 2]     = bf_lo(u);
        Hs[nl][kp * 2 + 1] = bf_hi(u);
    }
    __syncthreads();
    const int nl = tid >> 4;
    const int o  = tid & 15;
    float acc = 0.f;
#pragma unroll
    for (int k = 0; k < HID; k++) acc += Hs[nl][k] * Ws[k * 16 + o];
    float mx = acc;
#pragma unroll
    for (int m = 8; m >= 1; m >>= 1) mx = fmaxf(mx, __shfl_xor(mx, m));
    float ex = expf(acc - mx);
    float se = ex;
#pragma unroll
    for (int m = 8; m >= 1; m >>= 1) se += __shfl_xor(se, m);
    out[(n0 + nl) * 16 + o] = acc - mx - logf(se);
}

// ---------------------------------------------------------------------------

extern "C" void kernel_launch(void* const* d_in, const int* in_sizes, int n_in,
                              void* d_out, int out_size, void* d_ws, size_t ws_size,
                              hipStream_t stream) {
    const float* x     = (const float*)d_in[0];
    const int*   ei    = (const int*)d_in[1];
    const float* W_in  = (const float*)d_in[2];
    const float* cheb  = (const float*)d_in[3];
    const float* W_out = (const float*)d_in[4];
    float* out = (float*)d_out;

    char* p = (char*)d_ws;
    unsigned short* hA   = (unsigned short*)p; p += (size_t)N_NODES * HID * 2;   // 25.6 MB
    unsigned short* hB   = (unsigned short*)p; p += (size_t)N_NODES * HID * 2;   // 25.6 MB
    int*   col_sorted    = (int*)p;            p += (size_t)N_EDGES * 4;         // 6.4 MB
    unsigned short* Bmat = (unsigned short*)p; p += (size_t)2 * HID * KDIM * 2;  // 256 KB
    unsigned short* Wmat = (unsigned short*)p; p += (size_t)HID * KDIM * 2;      // 128 KB
    int*   row_start     = (int*)p;            p += (size_t)(N_NODES + 1) * 4;
    int*   bcnt          = (int*)p;            p += (size_t)NB * 16 * 4;         // 50 KB
    int*   bbase         = (int*)p;            p += (size_t)NB * 4;

    // bucket buffer aliases hA (dead until gemm_xw): 782*4096*4 = 12.8 MB < 25.6 MB
    unsigned* bbuf = (unsigned*)hA;

    const int nblk_gemm = (N_NODES + 127) / 128;       // 782
    const int nblk_edge = N_EDGES / 256;               // 6250
    const int nblk_spmm = (N_NODES + 3) / 4;           // 25000
    const int nblk_out  = N_NODES / 16;                // 6250

    hipMemsetAsync(bcnt, 0, (size_t)NB * 16 * 4, stream);
    bin_kernel<<<nblk_edge, 256, 0, stream>>>(ei, bcnt, bbuf);
    bscan_kernel<<<1, 1024, 0, stream>>>(bcnt, bbase);
    place_kernel<<<NB, 256, 0, stream>>>(bbuf, bcnt, bbase, row_start, col_sorted);
    repack_cheb<<<2 * HID * KDIM / 256, 256, 0, stream>>>(cheb, Bmat);
    repack_w<<<HID * KDIM / 256, 256, 0, stream>>>(W_in, Wmat);

    gemm_xw<<<nblk_gemm, 256, 0, stream>>>(x, Wmat, hA);
    spmm_gather<<<nblk_spmm, 256, 0, stream>>>(row_start, col_sorted, hA, hB);

    cheb_gemm<<<nblk_gemm, 256, 0, stream>>>(hB, Bmat, hA);                    // layer 0
    spmm_gather<<<nblk_spmm, 256, 0, stream>>>(row_start, col_sorted, hA, hB);

    cheb_gemm<<<nblk_gemm, 256, 0, stream>>>(hB, Bmat + HID * KDIM, hA);       // layer 1
    spmm_gather<<<nblk_spmm, 256, 0, stream>>>(row_start, col_sorted, hA, hB);

    out_kernel<<<nblk_out, 256, 0, stream>>>(hB, W_out, out);
}

// Round 7
// 685.517 us; speedup vs baseline: 1.2884x; 1.0529x over previous
//
#include <hip/hip_runtime.h>
#include <hip/hip_bf16.h>

#define N_NODES 100000
#define N_EDGES 1600000
#define IN_DIM  500
#define HID     128
#define KDIM    512   // HID * (DEG+1)
#define NB      782   // ceil(N_NODES/128) buckets
#define BCAP    4096  // bucket capacity (expected 2046, >20 sigma headroom)

typedef __attribute__((ext_vector_type(8))) short bf16x8;
typedef __attribute__((ext_vector_type(4))) float f32x4;

__device__ inline short f2bf(float x) {
    union { float f; unsigned u; } v; v.f = x;
    unsigned r = (v.u + 0x7FFFu + ((v.u >> 16) & 1u)) >> 16;  // RNE
    return (short)r;
}
__device__ inline float bf_lo(unsigned u) { union { unsigned u; float f; } v; v.u = u << 16; return v.f; }
__device__ inline float bf_hi(unsigned u) { union { unsigned u; float f; } v; v.u = u & 0xFFFF0000u; return v.f; }
__device__ inline float bf2f(unsigned short s) { union { unsigned u; float f; } v; v.u = ((unsigned)s) << 16; return v.f; }

// ---------------------------------------------------------------------------
// CSR build, two-pass binned (unchanged)
// ---------------------------------------------------------------------------

__global__ __launch_bounds__(256) void bin_kernel(const int* __restrict__ ei,
                                                  int* __restrict__ bcnt,
                                                  unsigned* __restrict__ buf) {
    int e = blockIdx.x * 256 + threadIdx.x;
    if (e < N_EDGES) {
        int r = ei[e];
        int c = ei[N_EDGES + e];
        int b = r >> 7;
        int p = atomicAdd(&bcnt[b * 16], 1);   // stride 64 B: spread L2 slices
        if (p < BCAP) buf[b * BCAP + p] = ((unsigned)(r & 127) << 17) | (unsigned)c;
    }
}

__global__ __launch_bounds__(1024) void bscan_kernel(const int* __restrict__ bcnt,
                                                     int* __restrict__ bbase) {
    __shared__ int buf[1024];
    const int tid = threadIdx.x;
    int v = (tid < NB) ? bcnt[tid * 16] : 0;
    buf[tid] = v;
    __syncthreads();
    for (int off = 1; off < 1024; off <<= 1) {
        int t = (tid >= off) ? buf[tid - off] : 0;
        __syncthreads();
        buf[tid] += t;
        __syncthreads();
    }
    if (tid < NB) bbase[tid] = buf[tid] - v;   // exclusive
}

__global__ __launch_bounds__(256) void place_kernel(const unsigned* __restrict__ buf,
                                                    const int* __restrict__ bcnt,
                                                    const int* __restrict__ bbase,
                                                    int* __restrict__ row_start,
                                                    int* __restrict__ col_sorted) {
    __shared__ int hist[128];
    __shared__ int scan[128];
    __shared__ int cur[128];
    const int b = blockIdx.x, tid = threadIdx.x;
    int cnt = bcnt[b * 16]; if (cnt > BCAP) cnt = BCAP;
    const int base = bbase[b];
    if (tid < 128) hist[tid] = 0;
    __syncthreads();
    for (int i = tid; i < cnt; i += 256)
        atomicAdd(&hist[buf[b * BCAP + i] >> 17], 1);
    __syncthreads();
    if (tid < 128) scan[tid] = hist[tid];
    __syncthreads();
    for (int off = 1; off < 128; off <<= 1) {
        int t = (tid < 128 && tid >= off) ? scan[tid - off] : 0;
        __syncthreads();
        if (tid < 128) scan[tid] += t;
        __syncthreads();
    }
    if (tid < 128) {
        int excl = scan[tid] - hist[tid] + base;
        cur[tid] = excl;
        int r = b * 128 + tid;
        if (r < N_NODES) row_start[r] = excl;
        if (r == N_NODES - 1) row_start[N_NODES] = excl + hist[tid];
    }
    __syncthreads();
    for (int i = tid; i < cnt; i += 256) {
        unsigned u = buf[b * BCAP + i];
        int rl = (int)(u >> 17);
        int c  = (int)(u & 0x1FFFFu);
        int pos = atomicAdd(&cur[rl], 1);
        col_sorted[pos] = c;
    }
}

// ---------------------------------------------------------------------------
// Weight repacks (once per launch): bf16, transposed to [n][k] GEMM-B layout
// ---------------------------------------------------------------------------
__global__ __launch_bounds__(256) void repack_cheb(const float* __restrict__ cheb,
                                                   unsigned short* __restrict__ Bmat) {
    int idx = blockIdx.x * 256 + threadIdx.x;   // < 2*128*512
    int l = idx >> 16;
    int rem = idx & 65535;
    int o = rem >> 9;
    int k = rem & 511;
    int i = k >> 2;
    int d = k & 3;
    Bmat[idx] = (unsigned short)f2bf(cheb[l * 65536 + i * 512 + o * 4 + d]);
}
__global__ __launch_bounds__(256) void repack_w(const float* __restrict__ W,
                                                unsigned short* __restrict__ Wmat) {
    int idx = blockIdx.x * 256 + threadIdx.x;   // < 128*512
    int o = idx >> 9;
    int k = idx & 511;
    Wmat[idx] = (k < IN_DIM) ? (unsigned short)f2bf(W[k * HID + o]) : 0;
}

// ---------------------------------------------------------------------------
// MFMA GEMM 1: h = x @ W_in  (dbuf LDS + register prefetch, unchanged)
// ---------------------------------------------------------------------------
__global__ __launch_bounds__(256, 3) void gemm_xw(const float* __restrict__ x,
                                                  const unsigned short* __restrict__ Wmat,
                                                  unsigned short* __restrict__ out) {
    __shared__ __align__(16) short As[2][128][40];   // [buf][m][k], row 80 B
    __shared__ __align__(16) short Bs[2][128][40];
    const int tid  = threadIdx.x;
    const int lane = tid & 63;
    const int wave = tid >> 6;
    const int quad = lane >> 4;
    const int l16  = lane & 15;
    const int n0   = blockIdx.x * 128;
    const int lr   = tid >> 1;
    const int lh   = tid & 1;
    const int bm   = tid >> 2;
    const int bkq  = tid & 3;

    int nA = n0 + lr; if (nA >= N_NODES) nA = N_NODES - 1;
    const float* __restrict__ xrow = x + (long)nA * IN_DIM;

    f32x4 acc[2][8];
#pragma unroll
    for (int mt = 0; mt < 2; mt++)
#pragma unroll
        for (int nt = 0; nt < 8; nt++)
#pragma unroll
            for (int r = 0; r < 4; r++) acc[mt][nt][r] = 0.f;

    auto loadA = [&](int kt, float (&v)[16]) {
        const int kb = kt * 32 + lh * 16;
        if (kb + 16 <= IN_DIM) {
            const float4* s4 = (const float4*)(xrow + kb);
            float4 a0 = s4[0], a1 = s4[1], a2 = s4[2], a3 = s4[3];
            v[0]=a0.x; v[1]=a0.y; v[2]=a0.z; v[3]=a0.w;
            v[4]=a1.x; v[5]=a1.y; v[6]=a1.z; v[7]=a1.w;
            v[8]=a2.x; v[9]=a2.y; v[10]=a2.z; v[11]=a2.w;
            v[12]=a3.x; v[13]=a3.y; v[14]=a3.z; v[15]=a3.w;
        } else {
#pragma unroll
            for (int q = 0; q < 16; q++) v[q] = (kb + q < IN_DIM) ? xrow[kb + q] : 0.f;
        }
    };
    auto loadB = [&](int kt, bf16x8 (&w)[2]) {
        w[0] = *(const bf16x8*)&Wmat[bm * 512 + kt * 32 + bkq * 8];
        w[1] = *(const bf16x8*)&Wmat[(bm + 64) * 512 + kt * 32 + bkq * 8];
    };
    auto storeA = [&](int buf, const float (&v)[16]) {
        short t[16];
#pragma unroll
        for (int q = 0; q < 16; q++) t[q] = f2bf(v[q]);
        *(bf16x8*)&As[buf][lr][lh * 16]     = *(bf16x8*)&t[0];
        *(bf16x8*)&As[buf][lr][lh * 16 + 8] = *(bf16x8*)&t[8];
    };
    auto storeB = [&](int buf, const bf16x8 (&w)[2]) {
        *(bf16x8*)&Bs[buf][bm][bkq * 8]      = w[0];
        *(bf16x8*)&Bs[buf][bm + 64][bkq * 8] = w[1];
    };
    auto mfmaTile = [&](int buf) {
        bf16x8 a0 = *(const bf16x8*)&As[buf][wave * 32 + l16][quad * 8];
        bf16x8 a1 = *(const bf16x8*)&As[buf][wave * 32 + 16 + l16][quad * 8];
#pragma unroll
        for (int nt = 0; nt < 8; nt++) {
            bf16x8 b = *(const bf16x8*)&Bs[buf][nt * 16 + l16][quad * 8];
            acc[0][nt] = __builtin_amdgcn_mfma_f32_16x16x32_bf16(a0, b, acc[0][nt], 0, 0, 0);
            acc[1][nt] = __builtin_amdgcn_mfma_f32_16x16x32_bf16(a1, b, acc[1][nt], 0, 0, 0);
        }
    };

    float  va[16], vb[16];
    bf16x8 wa[2],  wb[2];
    loadA(0, va); loadB(0, wa);
    for (int kt = 0; kt < 16; kt += 2) {
        storeA(0, va); storeB(0, wa);
        loadA(kt + 1, vb); loadB(kt + 1, wb);
        __syncthreads();
        mfmaTile(0);
        storeA(1, vb); storeB(1, wb);
        if (kt + 2 < 16) { loadA(kt + 2, va); loadB(kt + 2, wa); }
        __syncthreads();
        mfmaTile(1);
    }

#pragma unroll
    for (int mt = 0; mt < 2; mt++) {
        int mrow = n0 + wave * 32 + mt * 16 + quad * 4;
#pragma unroll
        for (int r = 0; r < 4; r++) {
            int n = mrow + r;
            if (n < N_NODES) {
#pragma unroll
                for (int nt = 0; nt < 8; nt++)
                    out[(long)n * HID + nt * 16 + l16] = (unsigned short)f2bf(acc[mt][nt][r]);
            }
        }
    }
}

// ---------------------------------------------------------------------------
// MFMA GEMM 2: out = Basis(h) @ C  (dbuf LDS + register prefetch, unchanged)
// ---------------------------------------------------------------------------
__global__ __launch_bounds__(256, 3) void cheb_gemm(const unsigned short* __restrict__ h,
                                                    const unsigned short* __restrict__ Bmat,
                                                    unsigned short* __restrict__ out) {
    __shared__ __align__(16) short As[2][128][40];
    __shared__ __align__(16) short Bs[2][128][40];
    const int tid  = threadIdx.x;
    const int lane = tid & 63;
    const int wave = tid >> 6;
    const int quad = lane >> 4;
    const int l16  = lane & 15;
    const int n0   = blockIdx.x * 128;
    const int lr   = tid >> 1;
    const int lh   = tid & 1;
    const int bm   = tid >> 2;
    const int bkq  = tid & 3;

    int nA = n0 + lr; if (nA >= N_NODES) nA = N_NODES - 1;
    const unsigned short* __restrict__ hrow = h + (long)nA * HID;

    f32x4 acc[2][8];
#pragma unroll
    for (int mt = 0; mt < 2; mt++)
#pragma unroll
        for (int nt = 0; nt < 8; nt++)
#pragma unroll
            for (int r = 0; r < 4; r++) acc[mt][nt][r] = 0.f;

    auto loadA = [&](int kt, ushort4& v) {
        v = *(const ushort4*)(hrow + kt * 8 + lh * 4);
    };
    auto loadB = [&](int kt, bf16x8 (&w)[2]) {
        w[0] = *(const bf16x8*)&Bmat[bm * 512 + kt * 32 + bkq * 8];
        w[1] = *(const bf16x8*)&Bmat[(bm + 64) * 512 + kt * 32 + bkq * 8];
    };
    auto storeA = [&](int buf, const ushort4& v) {
        float hx[4] = {bf2f(v.x), bf2f(v.y), bf2f(v.z), bf2f(v.w)};
        short t[16];
#pragma unroll
        for (int q = 0; q < 4; q++) {
            float xx = fminf(fmaxf(hx[q], -15.f), 15.f);
            float e  = __expf(2.f * xx);
            float tt = (e - 1.f) / (e + 1.f);     // tanh
            float T2 = 2.f * tt * tt - 1.f;
            float T3 = 2.f * tt * T2 - tt;
            t[q * 4 + 0] = (short)0x3F80;         // bf16(1.0)
            t[q * 4 + 1] = f2bf(tt);
            t[q * 4 + 2] = f2bf(T2);
            t[q * 4 + 3] = f2bf(T3);
        }
        *(bf16x8*)&As[buf][lr][lh * 16]     = *(bf16x8*)&t[0];
        *(bf16x8*)&As[buf][lr][lh * 16 + 8] = *(bf16x8*)&t[8];
    };
    auto storeB = [&](int buf, const bf16x8 (&w)[2]) {
        *(bf16x8*)&Bs[buf][bm][bkq * 8]      = w[0];
        *(bf16x8*)&Bs[buf][bm + 64][bkq * 8] = w[1];
    };
    auto mfmaTile = [&](int buf) {
        bf16x8 a0 = *(const bf16x8*)&As[buf][wave * 32 + l16][quad * 8];
        bf16x8 a1 = *(const bf16x8*)&As[buf][wave * 32 + 16 + l16][quad * 8];
#pragma unroll
        for (int nt = 0; nt < 8; nt++) {
            bf16x8 b = *(const bf16x8*)&Bs[buf][nt * 16 + l16][quad * 8];
            acc[0][nt] = __builtin_amdgcn_mfma_f32_16x16x32_bf16(a0, b, acc[0][nt], 0, 0, 0);
            acc[1][nt] = __builtin_amdgcn_mfma_f32_16x16x32_bf16(a1, b, acc[1][nt], 0, 0, 0);
        }
    };

    ushort4 va, vb;
    bf16x8  wa[2], wb[2];
    loadA(0, va); loadB(0, wa);
    for (int kt = 0; kt < 16; kt += 2) {
        storeA(0, va); storeB(0, wa);
        loadA(kt + 1, vb); loadB(kt + 1, wb);
        __syncthreads();
        mfmaTile(0);
        storeA(1, vb); storeB(1, wb);
        if (kt + 2 < 16) { loadA(kt + 2, va); loadB(kt + 2, wa); }
        __syncthreads();
        mfmaTile(1);
    }

#pragma unroll
    for (int mt = 0; mt < 2; mt++) {
        int mrow = n0 + wave * 32 + mt * 16 + quad * 4;
#pragma unroll
        for (int r = 0; r < 4; r++) {
            int n = mrow + r;
            if (n < N_NODES) {
#pragma unroll
                for (int nt = 0; nt < 8; nt++)
                    out[(long)n * HID + nt * 16 + l16] = (unsigned short)f2bf(acc[mt][nt][r]);
            }
        }
    }
}

// ---------------------------------------------------------------------------
// SpMM gather v2: wave/row; 16 lanes x uint4 (16 B) per edge -> 4 edges per
// vmem instruction, unrolled x2 (8 edges / 2 KB in flight per wave).
// Tail edges handled with mask folded into FMA. Butterfly over edge-slots.
// ---------------------------------------------------------------------------
__global__ __launch_bounds__(256) void spmm_gather(const int* __restrict__ row_start,
                                                   const int* __restrict__ col_sorted,
                                                   const unsigned short* __restrict__ h,
                                                   unsigned short* __restrict__ out) {
    const int wid  = (blockIdx.x * 256 + threadIdx.x) >> 6;   // row
    const int lane = threadIdx.x & 63;
    const int sub  = lane >> 4;        // edge slot 0..3
    const int fl   = lane & 15;        // 16-byte feature slice 0..15
    if (wid >= N_NODES) return;
    const int s = row_start[wid];
    const int e = row_start[wid + 1];
    const uint4* __restrict__ h4 = (const uint4*)h;   // one row = 16 uint4

    float a[8], b[8];
#pragma unroll
    for (int q = 0; q < 8; q++) { a[q] = 0.f; b[q] = 0.f; }

    int j = s;
    for (; j + 8 <= e; j += 8) {                 // all 8 edges valid
        int c0 = col_sorted[j + sub];
        int c1 = col_sorted[j + 4 + sub];
        uint4 u0 = h4[c0 * 16 + fl];
        uint4 u1 = h4[c1 * 16 + fl];
        a[0] += bf_lo(u0.x); a[1] += bf_hi(u0.x);
        a[2] += bf_lo(u0.y); a[3] += bf_hi(u0.y);
        a[4] += bf_lo(u0.z); a[5] += bf_hi(u0.z);
        a[6] += bf_lo(u0.w); a[7] += bf_hi(u0.w);
        b[0] += bf_lo(u1.x); b[1] += bf_hi(u1.x);
        b[2] += bf_lo(u1.y); b[3] += bf_hi(u1.y);
        b[4] += bf_lo(u1.z); b[5] += bf_hi(u1.z);
        b[6] += bf_lo(u1.w); b[7] += bf_hi(u1.w);
    }
    for (; j < e; j += 4) {                      // masked tail (<=2 rounds)
        int idx = j + sub;
        float m = (idx < e) ? 1.f : 0.f;
        int ci = (idx < e) ? idx : (e - 1);      // e > s here, safe
        int c = col_sorted[ci];
        uint4 u = h4[c * 16 + fl];
        a[0] = fmaf(m, bf_lo(u.x), a[0]); a[1] = fmaf(m, bf_hi(u.x), a[1]);
        a[2] = fmaf(m, bf_lo(u.y), a[2]); a[3] = fmaf(m, bf_hi(u.y), a[3]);
        a[4] = fmaf(m, bf_lo(u.z), a[4]); a[5] = fmaf(m, bf_hi(u.z), a[5]);
        a[6] = fmaf(m, bf_lo(u.w), a[6]); a[7] = fmaf(m, bf_hi(u.w), a[7]);
    }
#pragma unroll
    for (int q = 0; q < 8; q++) a[q] += b[q];
    // reduce across the 4 edge slots (lanes xor 16, 32)
#pragma unroll
    for (int q = 0; q < 8; q++) {
        a[q] += __shfl_xor(a[q], 16);
        a[q] += __shfl_xor(a[q], 32);
    }
    if (sub == 0) {
        unsigned w0 = (unsigned)(unsigned short)f2bf(a[0]) | ((unsigned)(unsigned short)f2bf(a[1]) << 16);
        unsigned w1 = (unsigned)(unsigned short)f2bf(a[2]) | ((unsigned)(unsigned short)f2bf(a[3]) << 16);
        unsigned w2 = (unsigned)(unsigned short)f2bf(a[4]) | ((unsigned)(unsigned short)f2bf(a[5]) << 16);
        unsigned w3 = (unsigned)(unsigned short)f2bf(a[6]) | ((unsigned)(unsigned short)f2bf(a[7]) << 16);
        uint4 pw; pw.x = w0; pw.y = w1; pw.z = w2; pw.w = w3;
        ((uint4*)out)[wid * 16 + fl] = pw;
    }
}

// ---------------------------------------------------------------------------
// Output GEMM (128->16) + log_softmax, fused. h bf16 in, f32 out.
// ---------------------------------------------------------------------------
__global__ __launch_bounds__(256) void out_kernel(const unsigned short* __restrict__ h,
                                                  const float* __restrict__ Wo,
                                                  float* __restrict__ out) {
    __shared__ float Ws[HID * 16];
    __shared__ float Hs[16][HID];
    const int tid = threadIdx.x;
    const int n0 = blockIdx.x * 16;
    for (int idx = tid; idx < HID * 16; idx += 256) Ws[idx] = Wo[idx];
    const unsigned* h1 = (const unsigned*)h;
    for (int idx = tid; idx < 16 * 64; idx += 256) {
        int nl = idx >> 6;
        int kp = idx & 63;
        unsigned u = h1[(n0 + nl) * 64 + kp];
        Hs[nl][kp * 2]     = bf_lo(u);
        Hs[nl][kp * 2 + 1] = bf_hi(u);
    }
    __syncthreads();
    const int nl = tid >> 4;
    const int o  = tid & 15;
    float acc = 0.f;
#pragma unroll
    for (int k = 0; k < HID; k++) acc += Hs[nl][k] * Ws[k * 16 + o];
    float mx = acc;
#pragma unroll
    for (int m = 8; m >= 1; m >>= 1) mx = fmaxf(mx, __shfl_xor(mx, m));
    float ex = expf(acc - mx);
    float se = ex;
#pragma unroll
    for (int m = 8; m >= 1; m >>= 1) se += __shfl_xor(se, m);
    out[(n0 + nl) * 16 + o] = acc - mx - logf(se);
}

// ---------------------------------------------------------------------------

extern "C" void kernel_launch(void* const* d_in, const int* in_sizes, int n_in,
                              void* d_out, int out_size, void* d_ws, size_t ws_size,
                              hipStream_t stream) {
    const float* x     = (const float*)d_in[0];
    const int*   ei    = (const int*)d_in[1];
    const float* W_in  = (const float*)d_in[2];
    const float* cheb  = (const float*)d_in[3];
    const float* W_out = (const float*)d_in[4];
    float* out = (float*)d_out;

    char* p = (char*)d_ws;
    unsigned short* hA   = (unsigned short*)p; p += (size_t)N_NODES * HID * 2;   // 25.6 MB
    unsigned short* hB   = (unsigned short*)p; p += (size_t)N_NODES * HID * 2;   // 25.6 MB
    int*   col_sorted    = (int*)p;            p += (size_t)N_EDGES * 4;         // 6.4 MB
    unsigned short* Bmat = (unsigned short*)p; p += (size_t)2 * HID * KDIM * 2;  // 256 KB
    unsigned short* Wmat = (unsigned short*)p; p += (size_t)HID * KDIM * 2;      // 128 KB
    int*   row_start     = (int*)p;            p += (size_t)(N_NODES + 1) * 4;
    int*   bcnt          = (int*)p;            p += (size_t)NB * 16 * 4;         // 50 KB
    int*   bbase         = (int*)p;            p += (size_t)NB * 4;

    // bucket buffer aliases hA (dead until gemm_xw): 782*4096*4 = 12.8 MB < 25.6 MB
    unsigned* bbuf = (unsigned*)hA;

    const int nblk_gemm = (N_NODES + 127) / 128;       // 782
    const int nblk_edge = N_EDGES / 256;               // 6250
    const int nblk_spmm = (N_NODES + 3) / 4;           // 25000
    const int nblk_out  = N_NODES / 16;                // 6250

    hipMemsetAsync(bcnt, 0, (size_t)NB * 16 * 4, stream);
    bin_kernel<<<nblk_edge, 256, 0, stream>>>(ei, bcnt, bbuf);
    bscan_kernel<<<1, 1024, 0, stream>>>(bcnt, bbase);
    place_kernel<<<NB, 256, 0, stream>>>(bbuf, bcnt, bbase, row_start, col_sorted);
    repack_cheb<<<2 * HID * KDIM / 256, 256, 0, stream>>>(cheb, Bmat);
    repack_w<<<HID * KDIM / 256, 256, 0, stream>>>(W_in, Wmat);

    gemm_xw<<<nblk_gemm, 256, 0, stream>>>(x, Wmat, hA);
    spmm_gather<<<nblk_spmm, 256, 0, stream>>>(row_start, col_sorted, hA, hB);

    cheb_gemm<<<nblk_gemm, 256, 0, stream>>>(hB, Bmat, hA);                    // layer 0
    spmm_gather<<<nblk_spmm, 256, 0, stream>>>(row_start, col_sorted, hA, hB);

    cheb_gemm<<<nblk_gemm, 256, 0, stream>>>(hB, Bmat + HID * KDIM, hA);       // layer 1
    spmm_gather<<<nblk_spmm, 256, 0, stream>>>(row_start, col_sorted, hA, hB);

    out_kernel<<<nblk_out, 256, 0, stream>>>(hB, W_out, out);
}

// Round 8
// 650.178 us; speedup vs baseline: 1.3585x; 1.0544x over previous
//
#include <hip/hip_runtime.h>
#include <hip/hip_bf16.h>

#define N_NODES 100000
#define N_EDGES 1600000
#define IN_DIM  500
#define HID     128
#define KDIM    512   // HID * (DEG+1)
#define NB      782   // ceil(N_NODES/128) buckets
#define BCAP    4096  // bucket capacity (expected 2046, >20 sigma headroom)

typedef __attribute__((ext_vector_type(8))) short bf16x8;
typedef __attribute__((ext_vector_type(4))) float f32x4;

__device__ inline short f2bf(float x) {
    union { float f; unsigned u; } v; v.f = x;
    unsigned r = (v.u + 0x7FFFu + ((v.u >> 16) & 1u)) >> 16;  // RNE
    return (short)r;
}
__device__ inline float bf_lo(unsigned u) { union { unsigned u; float f; } v; v.u = u << 16; return v.f; }
__device__ inline float bf_hi(unsigned u) { union { unsigned u; float f; } v; v.u = u & 0xFFFF0000u; return v.f; }
__device__ inline float bf2f(unsigned short s) { union { unsigned u; float f; } v; v.u = ((unsigned)s) << 16; return v.f; }

// ---------------------------------------------------------------------------
// CSR build, two-pass binned (unchanged)
// ---------------------------------------------------------------------------

__global__ __launch_bounds__(256) void bin_kernel(const int* __restrict__ ei,
                                                  int* __restrict__ bcnt,
                                                  unsigned* __restrict__ buf) {
    int e = blockIdx.x * 256 + threadIdx.x;
    if (e < N_EDGES) {
        int r = ei[e];
        int c = ei[N_EDGES + e];
        int b = r >> 7;
        int p = atomicAdd(&bcnt[b * 16], 1);   // stride 64 B: spread L2 slices
        if (p < BCAP) buf[b * BCAP + p] = ((unsigned)(r & 127) << 17) | (unsigned)c;
    }
}

__global__ __launch_bounds__(1024) void bscan_kernel(const int* __restrict__ bcnt,
                                                     int* __restrict__ bbase) {
    __shared__ int buf[1024];
    const int tid = threadIdx.x;
    int v = (tid < NB) ? bcnt[tid * 16] : 0;
    buf[tid] = v;
    __syncthreads();
    for (int off = 1; off < 1024; off <<= 1) {
        int t = (tid >= off) ? buf[tid - off] : 0;
        __syncthreads();
        buf[tid] += t;
        __syncthreads();
    }
    if (tid < NB) bbase[tid] = buf[tid] - v;   // exclusive
}

__global__ __launch_bounds__(256) void place_kernel(const unsigned* __restrict__ buf,
                                                    const int* __restrict__ bcnt,
                                                    const int* __restrict__ bbase,
                                                    int* __restrict__ row_start,
                                                    int* __restrict__ col_sorted) {
    __shared__ int hist[128];
    __shared__ int scan[128];
    __shared__ int cur[128];
    const int b = blockIdx.x, tid = threadIdx.x;
    int cnt = bcnt[b * 16]; if (cnt > BCAP) cnt = BCAP;
    const int base = bbase[b];
    if (tid < 128) hist[tid] = 0;
    __syncthreads();
    for (int i = tid; i < cnt; i += 256)
        atomicAdd(&hist[buf[b * BCAP + i] >> 17], 1);
    __syncthreads();
    if (tid < 128) scan[tid] = hist[tid];
    __syncthreads();
    for (int off = 1; off < 128; off <<= 1) {
        int t = (tid < 128 && tid >= off) ? scan[tid - off] : 0;
        __syncthreads();
        if (tid < 128) scan[tid] += t;
        __syncthreads();
    }
    if (tid < 128) {
        int excl = scan[tid] - hist[tid] + base;
        cur[tid] = excl;
        int r = b * 128 + tid;
        if (r < N_NODES) row_start[r] = excl;
        if (r == N_NODES - 1) row_start[N_NODES] = excl + hist[tid];
    }
    __syncthreads();
    for (int i = tid; i < cnt; i += 256) {
        unsigned u = buf[b * BCAP + i];
        int rl = (int)(u >> 17);
        int c  = (int)(u & 0x1FFFFu);
        int pos = atomicAdd(&cur[rl], 1);
        col_sorted[pos] = c;
    }
}

// ---------------------------------------------------------------------------
// Repacks (once per launch)
// ---------------------------------------------------------------------------
// cheb layer 0 only: [i][o][d] -> Bmat[o][k=i*4+d] bf16
__global__ __launch_bounds__(256) void repack_cheb(const float* __restrict__ cheb,
                                                   unsigned short* __restrict__ Bmat) {
    int idx = blockIdx.x * 256 + threadIdx.x;   // < 128*512
    int o = idx >> 9;
    int k = idx & 511;
    int i = k >> 2;
    int d = k & 3;
    Bmat[idx] = (unsigned short)f2bf(cheb[i * 512 + o * 4 + d]);
}
__global__ __launch_bounds__(256) void repack_w(const float* __restrict__ W,
                                                unsigned short* __restrict__ Wmat) {
    int idx = blockIdx.x * 256 + threadIdx.x;   // < 128*512
    int o = idx >> 9;
    int k = idx & 511;
    Wmat[idx] = (k < IN_DIM) ? (unsigned short)f2bf(W[k * HID + o]) : 0;
}
// C2W[o16][k] = sum_o cheb[l=1][i=k>>2][o][d=k&3] * W_out[o][o16]  (f32 math)
__global__ __launch_bounds__(256) void repack_c2w(const float* __restrict__ cheb,
                                                  const float* __restrict__ Wout,
                                                  unsigned short* __restrict__ C2W) {
    int idx = blockIdx.x * 256 + threadIdx.x;   // < 16*512
    if (idx >= 16 * 512) return;
    int o16 = idx >> 9;
    int k   = idx & 511;
    const float* cb = cheb + 65536 + (k >> 2) * 512 + (k & 3);
    float s = 0.f;
#pragma unroll 4
    for (int o = 0; o < 128; o++) s += cb[o * 4] * Wout[o * 16 + o16];
    C2W[o16 * 512 + k] = (unsigned short)f2bf(s);
}

// ---------------------------------------------------------------------------
// MFMA GEMM 1: h = x @ W_in  (dbuf LDS + register prefetch, unchanged)
// ---------------------------------------------------------------------------
__global__ __launch_bounds__(256, 3) void gemm_xw(const float* __restrict__ x,
                                                  const unsigned short* __restrict__ Wmat,
                                                  unsigned short* __restrict__ out) {
    __shared__ __align__(16) short As[2][128][40];   // [buf][m][k], row 80 B
    __shared__ __align__(16) short Bs[2][128][40];
    const int tid  = threadIdx.x;
    const int lane = tid & 63;
    const int wave = tid >> 6;
    const int quad = lane >> 4;
    const int l16  = lane & 15;
    const int n0   = blockIdx.x * 128;
    const int lr   = tid >> 1;
    const int lh   = tid & 1;
    const int bm   = tid >> 2;
    const int bkq  = tid & 3;

    int nA = n0 + lr; if (nA >= N_NODES) nA = N_NODES - 1;
    const float* __restrict__ xrow = x + (long)nA * IN_DIM;

    f32x4 acc[2][8];
#pragma unroll
    for (int mt = 0; mt < 2; mt++)
#pragma unroll
        for (int nt = 0; nt < 8; nt++)
#pragma unroll
            for (int r = 0; r < 4; r++) acc[mt][nt][r] = 0.f;

    auto loadA = [&](int kt, float (&v)[16]) {
        const int kb = kt * 32 + lh * 16;
        if (kb + 16 <= IN_DIM) {
            const float4* s4 = (const float4*)(xrow + kb);
            float4 a0 = s4[0], a1 = s4[1], a2 = s4[2], a3 = s4[3];
            v[0]=a0.x; v[1]=a0.y; v[2]=a0.z; v[3]=a0.w;
            v[4]=a1.x; v[5]=a1.y; v[6]=a1.z; v[7]=a1.w;
            v[8]=a2.x; v[9]=a2.y; v[10]=a2.z; v[11]=a2.w;
            v[12]=a3.x; v[13]=a3.y; v[14]=a3.z; v[15]=a3.w;
        } else {
#pragma unroll
            for (int q = 0; q < 16; q++) v[q] = (kb + q < IN_DIM) ? xrow[kb + q] : 0.f;
        }
    };
    auto loadB = [&](int kt, bf16x8 (&w)[2]) {
        w[0] = *(const bf16x8*)&Wmat[bm * 512 + kt * 32 + bkq * 8];
        w[1] = *(const bf16x8*)&Wmat[(bm + 64) * 512 + kt * 32 + bkq * 8];
    };
    auto storeA = [&](int buf, const float (&v)[16]) {
        short t[16];
#pragma unroll
        for (int q = 0; q < 16; q++) t[q] = f2bf(v[q]);
        *(bf16x8*)&As[buf][lr][lh * 16]     = *(bf16x8*)&t[0];
        *(bf16x8*)&As[buf][lr][lh * 16 + 8] = *(bf16x8*)&t[8];
    };
    auto storeB = [&](int buf, const bf16x8 (&w)[2]) {
        *(bf16x8*)&Bs[buf][bm][bkq * 8]      = w[0];
        *(bf16x8*)&Bs[buf][bm + 64][bkq * 8] = w[1];
    };
    auto mfmaTile = [&](int buf) {
        bf16x8 a0 = *(const bf16x8*)&As[buf][wave * 32 + l16][quad * 8];
        bf16x8 a1 = *(const bf16x8*)&As[buf][wave * 32 + 16 + l16][quad * 8];
#pragma unroll
        for (int nt = 0; nt < 8; nt++) {
            bf16x8 b = *(const bf16x8*)&Bs[buf][nt * 16 + l16][quad * 8];
            acc[0][nt] = __builtin_amdgcn_mfma_f32_16x16x32_bf16(a0, b, acc[0][nt], 0, 0, 0);
            acc[1][nt] = __builtin_amdgcn_mfma_f32_16x16x32_bf16(a1, b, acc[1][nt], 0, 0, 0);
        }
    };

    float  va[16], vb[16];
    bf16x8 wa[2],  wb[2];
    loadA(0, va); loadB(0, wa);
    for (int kt = 0; kt < 16; kt += 2) {
        storeA(0, va); storeB(0, wa);
        loadA(kt + 1, vb); loadB(kt + 1, wb);
        __syncthreads();
        mfmaTile(0);
        storeA(1, vb); storeB(1, wb);
        if (kt + 2 < 16) { loadA(kt + 2, va); loadB(kt + 2, wa); }
        __syncthreads();
        mfmaTile(1);
    }

#pragma unroll
    for (int mt = 0; mt < 2; mt++) {
        int mrow = n0 + wave * 32 + mt * 16 + quad * 4;
#pragma unroll
        for (int r = 0; r < 4; r++) {
            int n = mrow + r;
            if (n < N_NODES) {
#pragma unroll
                for (int nt = 0; nt < 8; nt++)
                    out[(long)n * HID + nt * 16 + l16] = (unsigned short)f2bf(acc[mt][nt][r]);
            }
        }
    }
}

// ---------------------------------------------------------------------------
// MFMA GEMM 2 (layer 0): out = Basis(h) @ C1  [N x 512]@[512 x 128]
// ---------------------------------------------------------------------------
__global__ __launch_bounds__(256, 3) void cheb_gemm(const unsigned short* __restrict__ h,
                                                    const unsigned short* __restrict__ Bmat,
                                                    unsigned short* __restrict__ out) {
    __shared__ __align__(16) short As[2][128][40];
    __shared__ __align__(16) short Bs[2][128][40];
    const int tid  = threadIdx.x;
    const int lane = tid & 63;
    const int wave = tid >> 6;
    const int quad = lane >> 4;
    const int l16  = lane & 15;
    const int n0   = blockIdx.x * 128;
    const int lr   = tid >> 1;
    const int lh   = tid & 1;
    const int bm   = tid >> 2;
    const int bkq  = tid & 3;

    int nA = n0 + lr; if (nA >= N_NODES) nA = N_NODES - 1;
    const unsigned short* __restrict__ hrow = h + (long)nA * HID;

    f32x4 acc[2][8];
#pragma unroll
    for (int mt = 0; mt < 2; mt++)
#pragma unroll
        for (int nt = 0; nt < 8; nt++)
#pragma unroll
            for (int r = 0; r < 4; r++) acc[mt][nt][r] = 0.f;

    auto loadA = [&](int kt, ushort4& v) {
        v = *(const ushort4*)(hrow + kt * 8 + lh * 4);
    };
    auto loadB = [&](int kt, bf16x8 (&w)[2]) {
        w[0] = *(const bf16x8*)&Bmat[bm * 512 + kt * 32 + bkq * 8];
        w[1] = *(const bf16x8*)&Bmat[(bm + 64) * 512 + kt * 32 + bkq * 8];
    };
    auto storeA = [&](int buf, const ushort4& v) {
        float hx[4] = {bf2f(v.x), bf2f(v.y), bf2f(v.z), bf2f(v.w)};
        short t[16];
#pragma unroll
        for (int q = 0; q < 4; q++) {
            float xx = fminf(fmaxf(hx[q], -15.f), 15.f);
            float e  = __expf(2.f * xx);
            float tt = (e - 1.f) / (e + 1.f);     // tanh
            float T2 = 2.f * tt * tt - 1.f;
            float T3 = 2.f * tt * T2 - tt;
            t[q * 4 + 0] = (short)0x3F80;         // bf16(1.0)
            t[q * 4 + 1] = f2bf(tt);
            t[q * 4 + 2] = f2bf(T2);
            t[q * 4 + 3] = f2bf(T3);
        }
        *(bf16x8*)&As[buf][lr][lh * 16]     = *(bf16x8*)&t[0];
        *(bf16x8*)&As[buf][lr][lh * 16 + 8] = *(bf16x8*)&t[8];
    };
    auto storeB = [&](int buf, const bf16x8 (&w)[2]) {
        *(bf16x8*)&Bs[buf][bm][bkq * 8]      = w[0];
        *(bf16x8*)&Bs[buf][bm + 64][bkq * 8] = w[1];
    };
    auto mfmaTile = [&](int buf) {
        bf16x8 a0 = *(const bf16x8*)&As[buf][wave * 32 + l16][quad * 8];
        bf16x8 a1 = *(const bf16x8*)&As[buf][wave * 32 + 16 + l16][quad * 8];
#pragma unroll
        for (int nt = 0; nt < 8; nt++) {
            bf16x8 b = *(const bf16x8*)&Bs[buf][nt * 16 + l16][quad * 8];
            acc[0][nt] = __builtin_amdgcn_mfma_f32_16x16x32_bf16(a0, b, acc[0][nt], 0, 0, 0);
            acc[1][nt] = __builtin_amdgcn_mfma_f32_16x16x32_bf16(a1, b, acc[1][nt], 0, 0, 0);
        }
    };

    ushort4 va, vb;
    bf16x8  wa[2], wb[2];
    loadA(0, va); loadB(0, wa);
    for (int kt = 0; kt < 16; kt += 2) {
        storeA(0, va); storeB(0, wa);
        loadA(kt + 1, vb); loadB(kt + 1, wb);
        __syncthreads();
        mfmaTile(0);
        storeA(1, vb); storeB(1, wb);
        if (kt + 2 < 16) { loadA(kt + 2, va); loadB(kt + 2, wa); }
        __syncthreads();
        mfmaTile(1);
    }

#pragma unroll
    for (int mt = 0; mt < 2; mt++) {
        int mrow = n0 + wave * 32 + mt * 16 + quad * 4;
#pragma unroll
        for (int r = 0; r < 4; r++) {
            int n = mrow + r;
            if (n < N_NODES) {
#pragma unroll
                for (int nt = 0; nt < 8; nt++)
                    out[(long)n * HID + nt * 16 + l16] = (unsigned short)f2bf(acc[mt][nt][r]);
            }
        }
    }
}

// ---------------------------------------------------------------------------
// MFMA GEMM 3 (layer 1 + W_out folded): z = Basis(h) @ C2W  [N x 512]@[512 x 16]
// B (16 KB) resident in LDS (padded rows: 520 shorts -> only 2-way conflicts);
// A dbuf staging as in cheb_gemm; f32 z output (feeds final gather directly).
// ---------------------------------------------------------------------------
__global__ __launch_bounds__(256, 3) void cheb16_gemm(const unsigned short* __restrict__ h,
                                                      const unsigned short* __restrict__ C2W,
                                                      float* __restrict__ z) {
    __shared__ __align__(16) short As[2][128][40];
    __shared__ __align__(16) short Bs16[16][520];
    const int tid  = threadIdx.x;
    const int lane = tid & 63;
    const int wave = tid >> 6;
    const int quad = lane >> 4;
    const int l16  = lane & 15;
    const int n0   = blockIdx.x * 128;
    const int lr   = tid >> 1;
    const int lh   = tid & 1;

    // load C2W fully into LDS: 16*512 ushorts, 32 per thread
    {
        int o16 = tid >> 4;            // 0..15
        int seg = tid & 15;            // 0..15, 32 shorts each
        *(bf16x8*)&Bs16[o16][seg * 32]      = *(const bf16x8*)&C2W[o16 * 512 + seg * 32];
        *(bf16x8*)&Bs16[o16][seg * 32 + 8]  = *(const bf16x8*)&C2W[o16 * 512 + seg * 32 + 8];
        *(bf16x8*)&Bs16[o16][seg * 32 + 16] = *(const bf16x8*)&C2W[o16 * 512 + seg * 32 + 16];
        *(bf16x8*)&Bs16[o16][seg * 32 + 24] = *(const bf16x8*)&C2W[o16 * 512 + seg * 32 + 24];
    }

    int nA = n0 + lr; if (nA >= N_NODES) nA = N_NODES - 1;
    const unsigned short* __restrict__ hrow = h + (long)nA * HID;

    f32x4 acc[2];
#pragma unroll
    for (int mt = 0; mt < 2; mt++)
#pragma unroll
        for (int r = 0; r < 4; r++) acc[mt][r] = 0.f;

    auto loadA = [&](int kt, ushort4& v) {
        v = *(const ushort4*)(hrow + kt * 8 + lh * 4);
    };
    auto storeA = [&](int buf, const ushort4& v) {
        float hx[4] = {bf2f(v.x), bf2f(v.y), bf2f(v.z), bf2f(v.w)};
        short t[16];
#pragma unroll
        for (int q = 0; q < 4; q++) {
            float xx = fminf(fmaxf(hx[q], -15.f), 15.f);
            float e  = __expf(2.f * xx);
            float tt = (e - 1.f) / (e + 1.f);
            float T2 = 2.f * tt * tt - 1.f;
            float T3 = 2.f * tt * T2 - tt;
            t[q * 4 + 0] = (short)0x3F80;
            t[q * 4 + 1] = f2bf(tt);
            t[q * 4 + 2] = f2bf(T2);
            t[q * 4 + 3] = f2bf(T3);
        }
        *(bf16x8*)&As[buf][lr][lh * 16]     = *(bf16x8*)&t[0];
        *(bf16x8*)&As[buf][lr][lh * 16 + 8] = *(bf16x8*)&t[8];
    };
    auto mfmaTile = [&](int buf, int kt) {
        bf16x8 a0 = *(const bf16x8*)&As[buf][wave * 32 + l16][quad * 8];
        bf16x8 a1 = *(const bf16x8*)&As[buf][wave * 32 + 16 + l16][quad * 8];
        bf16x8 b  = *(const bf16x8*)&Bs16[l16][kt * 32 + quad * 8];
        acc[0] = __builtin_amdgcn_mfma_f32_16x16x32_bf16(a0, b, acc[0], 0, 0, 0);
        acc[1] = __builtin_amdgcn_mfma_f32_16x16x32_bf16(a1, b, acc[1], 0, 0, 0);
    };

    ushort4 va, vb;
    loadA(0, va);
    for (int kt = 0; kt < 16; kt += 2) {
        storeA(0, va);
        loadA(kt + 1, vb);
        __syncthreads();
        mfmaTile(0, kt);
        storeA(1, vb);
        if (kt + 2 < 16) loadA(kt + 2, va);
        __syncthreads();
        mfmaTile(1, kt + 1);
    }

#pragma unroll
    for (int mt = 0; mt < 2; mt++) {
        int mrow = n0 + wave * 32 + mt * 16 + quad * 4;
#pragma unroll
        for (int r = 0; r < 4; r++) {
            int n = mrow + r;
            if (n < N_NODES) z[n * 16 + l16] = acc[mt][r];
        }
    }
}

// ---------------------------------------------------------------------------
// SpMM gather v2 (128-wide bf16): wave/row; 16 lanes x uint4 per edge,
// 4 edges/instr, unrolled x2. (spmm 1 and 2)
// ---------------------------------------------------------------------------
__global__ __launch_bounds__(256) void spmm_gather(const int* __restrict__ row_start,
                                                   const int* __restrict__ col_sorted,
                                                   const unsigned short* __restrict__ h,
                                                   unsigned short* __restrict__ out) {
    const int wid  = (blockIdx.x * 256 + threadIdx.x) >> 6;   // row
    const int lane = threadIdx.x & 63;
    const int sub  = lane >> 4;        // edge slot 0..3
    const int fl   = lane & 15;        // 16-byte feature slice 0..15
    if (wid >= N_NODES) return;
    const int s = row_start[wid];
    const int e = row_start[wid + 1];
    const uint4* __restrict__ h4 = (const uint4*)h;   // one row = 16 uint4

    float a[8], b[8];
#pragma unroll
    for (int q = 0; q < 8; q++) { a[q] = 0.f; b[q] = 0.f; }

    int j = s;
    for (; j + 8 <= e; j += 8) {
        int c0 = col_sorted[j + sub];
        int c1 = col_sorted[j + 4 + sub];
        uint4 u0 = h4[c0 * 16 + fl];
        uint4 u1 = h4[c1 * 16 + fl];
        a[0] += bf_lo(u0.x); a[1] += bf_hi(u0.x);
        a[2] += bf_lo(u0.y); a[3] += bf_hi(u0.y);
        a[4] += bf_lo(u0.z); a[5] += bf_hi(u0.z);
        a[6] += bf_lo(u0.w); a[7] += bf_hi(u0.w);
        b[0] += bf_lo(u1.x); b[1] += bf_hi(u1.x);
        b[2] += bf_lo(u1.y); b[3] += bf_hi(u1.y);
        b[4] += bf_lo(u1.z); b[5] += bf_hi(u1.z);
        b[6] += bf_lo(u1.w); b[7] += bf_hi(u1.w);
    }
    for (; j < e; j += 4) {
        int idx = j + sub;
        float m = (idx < e) ? 1.f : 0.f;
        int ci = (idx < e) ? idx : (e - 1);
        int c = col_sorted[ci];
        uint4 u = h4[c * 16 + fl];
        a[0] = fmaf(m, bf_lo(u.x), a[0]); a[1] = fmaf(m, bf_hi(u.x), a[1]);
        a[2] = fmaf(m, bf_lo(u.y), a[2]); a[3] = fmaf(m, bf_hi(u.y), a[3]);
        a[4] = fmaf(m, bf_lo(u.z), a[4]); a[5] = fmaf(m, bf_hi(u.z), a[5]);
        a[6] = fmaf(m, bf_lo(u.w), a[6]); a[7] = fmaf(m, bf_hi(u.w), a[7]);
    }
#pragma unroll
    for (int q = 0; q < 8; q++) a[q] += b[q];
#pragma unroll
    for (int q = 0; q < 8; q++) {
        a[q] += __shfl_xor(a[q], 16);
        a[q] += __shfl_xor(a[q], 32);
    }
    if (sub == 0) {
        unsigned w0 = (unsigned)(unsigned short)f2bf(a[0]) | ((unsigned)(unsigned short)f2bf(a[1]) << 16);
        unsigned w1 = (unsigned)(unsigned short)f2bf(a[2]) | ((unsigned)(unsigned short)f2bf(a[3]) << 16);
        unsigned w2 = (unsigned)(unsigned short)f2bf(a[4]) | ((unsigned)(unsigned short)f2bf(a[5]) << 16);
        unsigned w3 = (unsigned)(unsigned short)f2bf(a[6]) | ((unsigned)(unsigned short)f2bf(a[7]) << 16);
        uint4 pw; pw.x = w0; pw.y = w1; pw.z = w2; pw.w = w3;
        ((uint4*)out)[wid * 16 + fl] = pw;
    }
}

// ---------------------------------------------------------------------------
// Final spmm (16-wide f32) + log_softmax fused: out[row] = lsm(sum_c z[c])
// wave/row; 4 edge slots x 16 lanes x f32; butterfly over slots, then
// 16-lane shfl softmax; sub==0 lanes write the row (64 B).
// ---------------------------------------------------------------------------
__global__ __launch_bounds__(256) void spmm_out(const int* __restrict__ row_start,
                                                const int* __restrict__ col_sorted,
                                                const float* __restrict__ z,
                                                float* __restrict__ out) {
    const int wid  = (blockIdx.x * 256 + threadIdx.x) >> 6;
    const int lane = threadIdx.x & 63;
    const int sub  = lane >> 4;
    const int fl   = lane & 15;
    if (wid >= N_NODES) return;
    const int s = row_start[wid];
    const int e = row_start[wid + 1];

    float a0 = 0.f, a1 = 0.f;
    int j = s;
    for (; j + 8 <= e; j += 8) {
        int c0 = col_sorted[j + sub];
        int c1 = col_sorted[j + 4 + sub];
        a0 += z[c0 * 16 + fl];
        a1 += z[c1 * 16 + fl];
    }
    for (; j < e; j += 4) {
        int idx = j + sub;
        float m = (idx < e) ? 1.f : 0.f;
        int ci = (idx < e) ? idx : (e - 1);
        a0 = fmaf(m, z[col_sorted[ci] * 16 + fl], a0);
    }
    float v = a0 + a1;
    v += __shfl_xor(v, 16);
    v += __shfl_xor(v, 32);
    // log_softmax over the 16 cols (within each 16-lane group)
    float mx = v;
#pragma unroll
    for (int m = 8; m >= 1; m >>= 1) mx = fmaxf(mx, __shfl_xor(mx, m));
    float ex = expf(v - mx);
    float se = ex;
#pragma unroll
    for (int m = 8; m >= 1; m >>= 1) se += __shfl_xor(se, m);
    if (sub == 0) out[wid * 16 + fl] = v - mx - logf(se);
}

// ---------------------------------------------------------------------------

extern "C" void kernel_launch(void* const* d_in, const int* in_sizes, int n_in,
                              void* d_out, int out_size, void* d_ws, size_t ws_size,
                              hipStream_t stream) {
    const float* x     = (const float*)d_in[0];
    const int*   ei    = (const int*)d_in[1];
    const float* W_in  = (const float*)d_in[2];
    const float* cheb  = (const float*)d_in[3];
    const float* W_out = (const float*)d_in[4];
    float* out = (float*)d_out;

    char* p = (char*)d_ws;
    unsigned short* hA   = (unsigned short*)p; p += (size_t)N_NODES * HID * 2;   // 25.6 MB
    unsigned short* hB   = (unsigned short*)p; p += (size_t)N_NODES * HID * 2;   // 25.6 MB
    int*   col_sorted    = (int*)p;            p += (size_t)N_EDGES * 4;         // 6.4 MB
    unsigned short* Bmat = (unsigned short*)p; p += (size_t)HID * KDIM * 2;      // 128 KB (layer-0)
    unsigned short* Wmat = (unsigned short*)p; p += (size_t)HID * KDIM * 2;      // 128 KB
    unsigned short* C2W  = (unsigned short*)p; p += (size_t)16 * KDIM * 2;       // 16 KB
    float* zbuf          = (float*)p;          p += (size_t)N_NODES * 16 * 4;    // 6.4 MB
    int*   row_start     = (int*)p;            p += (size_t)(N_NODES + 1) * 4;
    int*   bcnt          = (int*)p;            p += (size_t)NB * 16 * 4;         // 50 KB
    int*   bbase         = (int*)p;            p += (size_t)NB * 4;

    // bucket buffer aliases hA (dead until gemm_xw): 782*4096*4 = 12.8 MB < 25.6 MB
    unsigned* bbuf = (unsigned*)hA;

    const int nblk_gemm = (N_NODES + 127) / 128;       // 782
    const int nblk_edge = N_EDGES / 256;               // 6250
    const int nblk_spmm = (N_NODES + 3) / 4;           // 25000

    hipMemsetAsync(bcnt, 0, (size_t)NB * 16 * 4, stream);
    bin_kernel<<<nblk_edge, 256, 0, stream>>>(ei, bcnt, bbuf);
    bscan_kernel<<<1, 1024, 0, stream>>>(bcnt, bbase);
    place_kernel<<<NB, 256, 0, stream>>>(bbuf, bcnt, bbase, row_start, col_sorted);
    repack_cheb<<<HID * KDIM / 256, 256, 0, stream>>>(cheb, Bmat);
    repack_w<<<HID * KDIM / 256, 256, 0, stream>>>(W_in, Wmat);
    repack_c2w<<<16 * KDIM / 256, 256, 0, stream>>>(cheb, W_out, C2W);

    gemm_xw<<<nblk_gemm, 256, 0, stream>>>(x, Wmat, hA);
    spmm_gather<<<nblk_spmm, 256, 0, stream>>>(row_start, col_sorted, hA, hB);

    cheb_gemm<<<nblk_gemm, 256, 0, stream>>>(hB, Bmat, hA);                    // layer 0
    spmm_gather<<<nblk_spmm, 256, 0, stream>>>(row_start, col_sorted, hA, hB);

    cheb16_gemm<<<nblk_gemm, 256, 0, stream>>>(hB, C2W, zbuf);                 // layer 1 + W_out
    spmm_out<<<nblk_spmm, 256, 0, stream>>>(row_start, col_sorted, zbuf, out); // spmm + lsm
}

// Round 9
// 649.942 us; speedup vs baseline: 1.3590x; 1.0004x over previous
//
#include <hip/hip_runtime.h>
#include <hip/hip_bf16.h>

#define N_NODES 100000
#define N_EDGES 1600000
#define IN_DIM  500
#define HID     128
#define KDIM    512   // HID * (DEG+1)
#define NB      782   // ceil(N_NODES/128) buckets
#define BCAP    4096  // bucket capacity (expected 2046, >20 sigma headroom)

typedef __attribute__((ext_vector_type(8))) short bf16x8;
typedef __attribute__((ext_vector_type(4))) float f32x4;

__device__ inline short f2bf(float x) {
    union { float f; unsigned u; } v; v.f = x;
    unsigned r = (v.u + 0x7FFFu + ((v.u >> 16) & 1u)) >> 16;  // RNE
    return (short)r;
}
__device__ inline float bf_lo(unsigned u) { union { unsigned u; float f; } v; v.u = u << 16; return v.f; }
__device__ inline float bf_hi(unsigned u) { union { unsigned u; float f; } v; v.u = u & 0xFFFF0000u; return v.f; }
__device__ inline float bf2f(unsigned short s) { union { unsigned u; float f; } v; v.u = ((unsigned)s) << 16; return v.f; }

// ---------------------------------------------------------------------------
// CSR build, two-pass binned (unchanged)
// ---------------------------------------------------------------------------

__global__ __launch_bounds__(256) void bin_kernel(const int* __restrict__ ei,
                                                  int* __restrict__ bcnt,
                                                  unsigned* __restrict__ buf) {
    int e = blockIdx.x * 256 + threadIdx.x;
    if (e < N_EDGES) {
        int r = ei[e];
        int c = ei[N_EDGES + e];
        int b = r >> 7;
        int p = atomicAdd(&bcnt[b * 16], 1);   // stride 64 B: spread L2 slices
        if (p < BCAP) buf[b * BCAP + p] = ((unsigned)(r & 127) << 17) | (unsigned)c;
    }
}

__global__ __launch_bounds__(1024) void bscan_kernel(const int* __restrict__ bcnt,
                                                     int* __restrict__ bbase) {
    __shared__ int buf[1024];
    const int tid = threadIdx.x;
    int v = (tid < NB) ? bcnt[tid * 16] : 0;
    buf[tid] = v;
    __syncthreads();
    for (int off = 1; off < 1024; off <<= 1) {
        int t = (tid >= off) ? buf[tid - off] : 0;
        __syncthreads();
        buf[tid] += t;
        __syncthreads();
    }
    if (tid < NB) bbase[tid] = buf[tid] - v;   // exclusive
}

__global__ __launch_bounds__(256) void place_kernel(const unsigned* __restrict__ buf,
                                                    const int* __restrict__ bcnt,
                                                    const int* __restrict__ bbase,
                                                    int* __restrict__ row_start,
                                                    int* __restrict__ col_sorted) {
    __shared__ int hist[128];
    __shared__ int scan[128];
    __shared__ int cur[128];
    const int b = blockIdx.x, tid = threadIdx.x;
    int cnt = bcnt[b * 16]; if (cnt > BCAP) cnt = BCAP;
    const int base = bbase[b];
    if (tid < 128) hist[tid] = 0;
    __syncthreads();
    for (int i = tid; i < cnt; i += 256)
        atomicAdd(&hist[buf[b * BCAP + i] >> 17], 1);
    __syncthreads();
    if (tid < 128) scan[tid] = hist[tid];
    __syncthreads();
    for (int off = 1; off < 128; off <<= 1) {
        int t = (tid < 128 && tid >= off) ? scan[tid - off] : 0;
        __syncthreads();
        if (tid < 128) scan[tid] += t;
        __syncthreads();
    }
    if (tid < 128) {
        int excl = scan[tid] - hist[tid] + base;
        cur[tid] = excl;
        int r = b * 128 + tid;
        if (r < N_NODES) row_start[r] = excl;
        if (r == N_NODES - 1) row_start[N_NODES] = excl + hist[tid];
    }
    __syncthreads();
    for (int i = tid; i < cnt; i += 256) {
        unsigned u = buf[b * BCAP + i];
        int rl = (int)(u >> 17);
        int c  = (int)(u & 0x1FFFFu);
        int pos = atomicAdd(&cur[rl], 1);
        col_sorted[pos] = c;
    }
}

// ---------------------------------------------------------------------------
// Repacks (once per launch)
// ---------------------------------------------------------------------------
__global__ __launch_bounds__(256) void repack_cheb(const float* __restrict__ cheb,
                                                   unsigned short* __restrict__ Bmat) {
    int idx = blockIdx.x * 256 + threadIdx.x;   // < 128*512
    int o = idx >> 9;
    int k = idx & 511;
    int i = k >> 2;
    int d = k & 3;
    Bmat[idx] = (unsigned short)f2bf(cheb[i * 512 + o * 4 + d]);
}
__global__ __launch_bounds__(256) void repack_w(const float* __restrict__ W,
                                                unsigned short* __restrict__ Wmat) {
    int idx = blockIdx.x * 256 + threadIdx.x;   // < 128*512
    int o = idx >> 9;
    int k = idx & 511;
    Wmat[idx] = (k < IN_DIM) ? (unsigned short)f2bf(W[k * HID + o]) : 0;
}
__global__ __launch_bounds__(256) void repack_c2w(const float* __restrict__ cheb,
                                                  const float* __restrict__ Wout,
                                                  unsigned short* __restrict__ C2W) {
    int idx = blockIdx.x * 256 + threadIdx.x;   // < 16*512
    if (idx >= 16 * 512) return;
    int o16 = idx >> 9;
    int k   = idx & 511;
    const float* cb = cheb + 65536 + (k >> 2) * 512 + (k & 3);
    float s = 0.f;
#pragma unroll 4
    for (int o = 0; o < 128; o++) s += cb[o * 4] * Wout[o * 16 + o16];
    C2W[o16 * 512 + k] = (unsigned short)f2bf(s);
}

// ---------------------------------------------------------------------------
// MFMA GEMM 1: h = x @ W_in  [100000 x 500(512)] @ [500 x 128] -> bf16
// 64x128 tile (grid 1563 -> ~5 blocks/CU, ~20 waves/CU), BK=32,
// dbuf LDS + register prefetch. Wave w: rows w*16..+15, 8 n-frags.
// ---------------------------------------------------------------------------
__global__ __launch_bounds__(256, 4) void gemm_xw(const float* __restrict__ x,
                                                  const unsigned short* __restrict__ Wmat,
                                                  unsigned short* __restrict__ out) {
    __shared__ __align__(16) short As[2][64][40];    // 10.25 KB
    __shared__ __align__(16) short Bs[2][128][40];   // 20.5  KB
    const int tid  = threadIdx.x;
    const int lane = tid & 63;
    const int wave = tid >> 6;
    const int quad = lane >> 4;
    const int l16  = lane & 15;
    const int n0   = blockIdx.x * 64;
    const int ar   = tid >> 2;     // A row 0..63
    const int ah   = tid & 3;      // 8-float segment
    const int br   = tid >> 1;     // B row 0..127
    const int bh   = tid & 1;      // 16-short segment

    int nA = n0 + ar; if (nA >= N_NODES) nA = N_NODES - 1;
    const float* __restrict__ xrow = x + (long)nA * IN_DIM;

    f32x4 acc[8];
#pragma unroll
    for (int nt = 0; nt < 8; nt++)
#pragma unroll
        for (int r = 0; r < 4; r++) acc[nt][r] = 0.f;

    auto loadA = [&](int kt, float (&v)[8]) {
        const int kb = kt * 32 + ah * 8;
        if (kb + 8 <= IN_DIM) {
            const float4* s4 = (const float4*)(xrow + kb);
            float4 a0 = s4[0], a1 = s4[1];
            v[0]=a0.x; v[1]=a0.y; v[2]=a0.z; v[3]=a0.w;
            v[4]=a1.x; v[5]=a1.y; v[6]=a1.z; v[7]=a1.w;
        } else {
#pragma unroll
            for (int q = 0; q < 8; q++) v[q] = (kb + q < IN_DIM) ? xrow[kb + q] : 0.f;
        }
    };
    auto loadB = [&](int kt, bf16x8 (&w)[2]) {
        w[0] = *(const bf16x8*)&Wmat[br * 512 + kt * 32 + bh * 16];
        w[1] = *(const bf16x8*)&Wmat[br * 512 + kt * 32 + bh * 16 + 8];
    };
    auto storeA = [&](int buf, const float (&v)[8]) {
        short t[8];
#pragma unroll
        for (int q = 0; q < 8; q++) t[q] = f2bf(v[q]);
        *(bf16x8*)&As[buf][ar][ah * 8] = *(bf16x8*)&t[0];
    };
    auto storeB = [&](int buf, const bf16x8 (&w)[2]) {
        *(bf16x8*)&Bs[buf][br][bh * 16]     = w[0];
        *(bf16x8*)&Bs[buf][br][bh * 16 + 8] = w[1];
    };
    auto mfmaTile = [&](int buf) {
        bf16x8 a = *(const bf16x8*)&As[buf][wave * 16 + l16][quad * 8];
#pragma unroll
        for (int nt = 0; nt < 8; nt++) {
            bf16x8 b = *(const bf16x8*)&Bs[buf][nt * 16 + l16][quad * 8];
            acc[nt] = __builtin_amdgcn_mfma_f32_16x16x32_bf16(a, b, acc[nt], 0, 0, 0);
        }
    };

    float  va[8], vb[8];
    bf16x8 wa[2], wb[2];
    loadA(0, va); loadB(0, wa);
    for (int kt = 0; kt < 16; kt += 2) {
        storeA(0, va); storeB(0, wa);
        loadA(kt + 1, vb); loadB(kt + 1, wb);
        __syncthreads();
        mfmaTile(0);
        storeA(1, vb); storeB(1, wb);
        if (kt + 2 < 16) { loadA(kt + 2, va); loadB(kt + 2, wa); }
        __syncthreads();
        mfmaTile(1);
    }

    {
        int mrow = n0 + wave * 16 + quad * 4;
#pragma unroll
        for (int r = 0; r < 4; r++) {
            int n = mrow + r;
            if (n < N_NODES) {
#pragma unroll
                for (int nt = 0; nt < 8; nt++)
                    out[(long)n * HID + nt * 16 + l16] = (unsigned short)f2bf(acc[nt][r]);
            }
        }
    }
}

// ---------------------------------------------------------------------------
// MFMA GEMM 2 (layer 0): out = Basis(h) @ C1  [N x 512]@[512 x 128]
// 64x128 tile; basis on the fly in A staging (2 features/thread/tile).
// ---------------------------------------------------------------------------
__global__ __launch_bounds__(256, 4) void cheb_gemm(const unsigned short* __restrict__ h,
                                                    const unsigned short* __restrict__ Bmat,
                                                    unsigned short* __restrict__ out) {
    __shared__ __align__(16) short As[2][64][40];
    __shared__ __align__(16) short Bs[2][128][40];
    const int tid  = threadIdx.x;
    const int lane = tid & 63;
    const int wave = tid >> 6;
    const int quad = lane >> 4;
    const int l16  = lane & 15;
    const int n0   = blockIdx.x * 64;
    const int ar   = tid >> 2;
    const int sub  = tid & 3;      // 2 h-features each
    const int br   = tid >> 1;
    const int bh   = tid & 1;

    int nA = n0 + ar; if (nA >= N_NODES) nA = N_NODES - 1;
    const unsigned short* __restrict__ hrow = h + (long)nA * HID;

    f32x4 acc[8];
#pragma unroll
    for (int nt = 0; nt < 8; nt++)
#pragma unroll
        for (int r = 0; r < 4; r++) acc[nt][r] = 0.f;

    auto loadA = [&](int kt, unsigned& v) {
        v = *(const unsigned*)(hrow + kt * 8 + sub * 2);   // 2 bf16 features
    };
    auto loadB = [&](int kt, bf16x8 (&w)[2]) {
        w[0] = *(const bf16x8*)&Bmat[br * 512 + kt * 32 + bh * 16];
        w[1] = *(const bf16x8*)&Bmat[br * 512 + kt * 32 + bh * 16 + 8];
    };
    auto storeA = [&](int buf, unsigned v) {
        float hx[2] = {bf_lo(v), bf_hi(v)};
        short t[8];
#pragma unroll
        for (int q = 0; q < 2; q++) {
            float xx = fminf(fmaxf(hx[q], -15.f), 15.f);
            float e  = __expf(2.f * xx);
            float tt = (e - 1.f) / (e + 1.f);     // tanh
            float T2 = 2.f * tt * tt - 1.f;
            float T3 = 2.f * tt * T2 - tt;
            t[q * 4 + 0] = (short)0x3F80;         // bf16(1.0)
            t[q * 4 + 1] = f2bf(tt);
            t[q * 4 + 2] = f2bf(T2);
            t[q * 4 + 3] = f2bf(T3);
        }
        *(bf16x8*)&As[buf][ar][sub * 8] = *(bf16x8*)&t[0];
    };
    auto storeB = [&](int buf, const bf16x8 (&w)[2]) {
        *(bf16x8*)&Bs[buf][br][bh * 16]     = w[0];
        *(bf16x8*)&Bs[buf][br][bh * 16 + 8] = w[1];
    };
    auto mfmaTile = [&](int buf) {
        bf16x8 a = *(const bf16x8*)&As[buf][wave * 16 + l16][quad * 8];
#pragma unroll
        for (int nt = 0; nt < 8; nt++) {
            bf16x8 b = *(const bf16x8*)&Bs[buf][nt * 16 + l16][quad * 8];
            acc[nt] = __builtin_amdgcn_mfma_f32_16x16x32_bf16(a, b, acc[nt], 0, 0, 0);
        }
    };

    unsigned va, vb;
    bf16x8   wa[2], wb[2];
    loadA(0, va); loadB(0, wa);
    for (int kt = 0; kt < 16; kt += 2) {
        storeA(0, va); storeB(0, wa);
        loadA(kt + 1, vb); loadB(kt + 1, wb);
        __syncthreads();
        mfmaTile(0);
        storeA(1, vb); storeB(1, wb);
        if (kt + 2 < 16) { loadA(kt + 2, va); loadB(kt + 2, wa); }
        __syncthreads();
        mfmaTile(1);
    }

    {
        int mrow = n0 + wave * 16 + quad * 4;
#pragma unroll
        for (int r = 0; r < 4; r++) {
            int n = mrow + r;
            if (n < N_NODES) {
#pragma unroll
                for (int nt = 0; nt < 8; nt++)
                    out[(long)n * HID + nt * 16 + l16] = (unsigned short)f2bf(acc[nt][r]);
            }
        }
    }
}

// ---------------------------------------------------------------------------
// MFMA GEMM 3 (layer 1 + W_out folded): z = Basis(h) @ C2W  [N x 512]@[512 x 16]
// 64-row tile; B (16 KB) LDS-resident; A dbuf as cheb_gemm; f32 z out.
// ---------------------------------------------------------------------------
__global__ __launch_bounds__(256, 4) void cheb16_gemm(const unsigned short* __restrict__ h,
                                                      const unsigned short* __restrict__ C2W,
                                                      float* __restrict__ z) {
    __shared__ __align__(16) short As[2][64][40];
    __shared__ __align__(16) short Bs16[16][520];
    const int tid  = threadIdx.x;
    const int lane = tid & 63;
    const int wave = tid >> 6;
    const int quad = lane >> 4;
    const int l16  = lane & 15;
    const int n0   = blockIdx.x * 64;
    const int ar   = tid >> 2;
    const int sub  = tid & 3;

    {
        int o16 = tid >> 4;
        int seg = tid & 15;
        *(bf16x8*)&Bs16[o16][seg * 32]      = *(const bf16x8*)&C2W[o16 * 512 + seg * 32];
        *(bf16x8*)&Bs16[o16][seg * 32 + 8]  = *(const bf16x8*)&C2W[o16 * 512 + seg * 32 + 8];
        *(bf16x8*)&Bs16[o16][seg * 32 + 16] = *(const bf16x8*)&C2W[o16 * 512 + seg * 32 + 16];
        *(bf16x8*)&Bs16[o16][seg * 32 + 24] = *(const bf16x8*)&C2W[o16 * 512 + seg * 32 + 24];
    }

    int nA = n0 + ar; if (nA >= N_NODES) nA = N_NODES - 1;
    const unsigned short* __restrict__ hrow = h + (long)nA * HID;

    f32x4 acc;
#pragma unroll
    for (int r = 0; r < 4; r++) acc[r] = 0.f;

    auto loadA = [&](int kt, unsigned& v) {
        v = *(const unsigned*)(hrow + kt * 8 + sub * 2);
    };
    auto storeA = [&](int buf, unsigned v) {
        float hx[2] = {bf_lo(v), bf_hi(v)};
        short t[8];
#pragma unroll
        for (int q = 0; q < 2; q++) {
            float xx = fminf(fmaxf(hx[q], -15.f), 15.f);
            float e  = __expf(2.f * xx);
            float tt = (e - 1.f) / (e + 1.f);
            float T2 = 2.f * tt * tt - 1.f;
            float T3 = 2.f * tt * T2 - tt;
            t[q * 4 + 0] = (short)0x3F80;
            t[q * 4 + 1] = f2bf(tt);
            t[q * 4 + 2] = f2bf(T2);
            t[q * 4 + 3] = f2bf(T3);
        }
        *(bf16x8*)&As[buf][ar][sub * 8] = *(bf16x8*)&t[0];
    };
    auto mfmaTile = [&](int buf, int kt) {
        bf16x8 a = *(const bf16x8*)&As[buf][wave * 16 + l16][quad * 8];
        bf16x8 b = *(const bf16x8*)&Bs16[l16][kt * 32 + quad * 8];
        acc = __builtin_amdgcn_mfma_f32_16x16x32_bf16(a, b, acc, 0, 0, 0);
    };

    unsigned va, vb;
    loadA(0, va);
    for (int kt = 0; kt < 16; kt += 2) {
        storeA(0, va);
        loadA(kt + 1, vb);
        __syncthreads();
        mfmaTile(0, kt);
        storeA(1, vb);
        if (kt + 2 < 16) loadA(kt + 2, va);
        __syncthreads();
        mfmaTile(1, kt + 1);
    }

    {
        int mrow = n0 + wave * 16 + quad * 4;
#pragma unroll
        for (int r = 0; r < 4; r++) {
            int n = mrow + r;
            if (n < N_NODES) z[n * 16 + l16] = acc[r];
        }
    }
}

// ---------------------------------------------------------------------------
// SpMM gather v2 (128-wide bf16): wave/row; 16 lanes x uint4 per edge,
// 4 edges/instr, unrolled x2. (spmm 1 and 2)
// ---------------------------------------------------------------------------
__global__ __launch_bounds__(256) void spmm_gather(const int* __restrict__ row_start,
                                                   const int* __restrict__ col_sorted,
                                                   const unsigned short* __restrict__ h,
                                                   unsigned short* __restrict__ out) {
    const int wid  = (blockIdx.x * 256 + threadIdx.x) >> 6;   // row
    const int lane = threadIdx.x & 63;
    const int sub  = lane >> 4;        // edge slot 0..3
    const int fl   = lane & 15;        // 16-byte feature slice 0..15
    if (wid >= N_NODES) return;
    const int s = row_start[wid];
    const int e = row_start[wid + 1];
    const uint4* __restrict__ h4 = (const uint4*)h;   // one row = 16 uint4

    float a[8], b[8];
#pragma unroll
    for (int q = 0; q < 8; q++) { a[q] = 0.f; b[q] = 0.f; }

    int j = s;
    for (; j + 8 <= e; j += 8) {
        int c0 = col_sorted[j + sub];
        int c1 = col_sorted[j + 4 + sub];
        uint4 u0 = h4[c0 * 16 + fl];
        uint4 u1 = h4[c1 * 16 + fl];
        a[0] += bf_lo(u0.x); a[1] += bf_hi(u0.x);
        a[2] += bf_lo(u0.y); a[3] += bf_hi(u0.y);
        a[4] += bf_lo(u0.z); a[5] += bf_hi(u0.z);
        a[6] += bf_lo(u0.w); a[7] += bf_hi(u0.w);
        b[0] += bf_lo(u1.x); b[1] += bf_hi(u1.x);
        b[2] += bf_lo(u1.y); b[3] += bf_hi(u1.y);
        b[4] += bf_lo(u1.z); b[5] += bf_hi(u1.z);
        b[6] += bf_lo(u1.w); b[7] += bf_hi(u1.w);
    }
    for (; j < e; j += 4) {
        int idx = j + sub;
        float m = (idx < e) ? 1.f : 0.f;
        int ci = (idx < e) ? idx : (e - 1);
        int c = col_sorted[ci];
        uint4 u = h4[c * 16 + fl];
        a[0] = fmaf(m, bf_lo(u.x), a[0]); a[1] = fmaf(m, bf_hi(u.x), a[1]);
        a[2] = fmaf(m, bf_lo(u.y), a[2]); a[3] = fmaf(m, bf_hi(u.y), a[3]);
        a[4] = fmaf(m, bf_lo(u.z), a[4]); a[5] = fmaf(m, bf_hi(u.z), a[5]);
        a[6] = fmaf(m, bf_lo(u.w), a[6]); a[7] = fmaf(m, bf_hi(u.w), a[7]);
    }
#pragma unroll
    for (int q = 0; q < 8; q++) a[q] += b[q];
#pragma unroll
    for (int q = 0; q < 8; q++) {
        a[q] += __shfl_xor(a[q], 16);
        a[q] += __shfl_xor(a[q], 32);
    }
    if (sub == 0) {
        unsigned w0 = (unsigned)(unsigned short)f2bf(a[0]) | ((unsigned)(unsigned short)f2bf(a[1]) << 16);
        unsigned w1 = (unsigned)(unsigned short)f2bf(a[2]) | ((unsigned)(unsigned short)f2bf(a[3]) << 16);
        unsigned w2 = (unsigned)(unsigned short)f2bf(a[4]) | ((unsigned)(unsigned short)f2bf(a[5]) << 16);
        unsigned w3 = (unsigned)(unsigned short)f2bf(a[6]) | ((unsigned)(unsigned short)f2bf(a[7]) << 16);
        uint4 pw; pw.x = w0; pw.y = w1; pw.z = w2; pw.w = w3;
        ((uint4*)out)[wid * 16 + fl] = pw;
    }
}

// ---------------------------------------------------------------------------
// Final spmm (16-wide f32) + log_softmax fused (unchanged)
// ---------------------------------------------------------------------------
__global__ __launch_bounds__(256) void spmm_out(const int* __restrict__ row_start,
                                                const int* __restrict__ col_sorted,
                                                const float* __restrict__ z,
                                                float* __restrict__ out) {
    const int wid  = (blockIdx.x * 256 + threadIdx.x) >> 6;
    const int lane = threadIdx.x & 63;
    const int sub  = lane >> 4;
    const int fl   = lane & 15;
    if (wid >= N_NODES) return;
    const int s = row_start[wid];
    const int e = row_start[wid + 1];

    float a0 = 0.f, a1 = 0.f;
    int j = s;
    for (; j + 8 <= e; j += 8) {
        int c0 = col_sorted[j + sub];
        int c1 = col_sorted[j + 4 + sub];
        a0 += z[c0 * 16 + fl];
        a1 += z[c1 * 16 + fl];
    }
    for (; j < e; j += 4) {
        int idx = j + sub;
        float m = (idx < e) ? 1.f : 0.f;
        int ci = (idx < e) ? idx : (e - 1);
        a0 = fmaf(m, z[col_sorted[ci] * 16 + fl], a0);
    }
    float v = a0 + a1;
    v += __shfl_xor(v, 16);
    v += __shfl_xor(v, 32);
    float mx = v;
#pragma unroll
    for (int m = 8; m >= 1; m >>= 1) mx = fmaxf(mx, __shfl_xor(mx, m));
    float ex = expf(v - mx);
    float se = ex;
#pragma unroll
    for (int m = 8; m >= 1; m >>= 1) se += __shfl_xor(se, m);
    if (sub == 0) out[wid * 16 + fl] = v - mx - logf(se);
}

// ---------------------------------------------------------------------------

extern "C" void kernel_launch(void* const* d_in, const int* in_sizes, int n_in,
                              void* d_out, int out_size, void* d_ws, size_t ws_size,
                              hipStream_t stream) {
    const float* x     = (const float*)d_in[0];
    const int*   ei    = (const int*)d_in[1];
    const float* W_in  = (const float*)d_in[2];
    const float* cheb  = (const float*)d_in[3];
    const float* W_out = (const float*)d_in[4];
    float* out = (float*)d_out;

    char* p = (char*)d_ws;
    unsigned short* hA   = (unsigned short*)p; p += (size_t)N_NODES * HID * 2;   // 25.6 MB
    unsigned short* hB   = (unsigned short*)p; p += (size_t)N_NODES * HID * 2;   // 25.6 MB
    int*   col_sorted    = (int*)p;            p += (size_t)N_EDGES * 4;         // 6.4 MB
    unsigned short* Bmat = (unsigned short*)p; p += (size_t)HID * KDIM * 2;      // 128 KB (layer-0)
    unsigned short* Wmat = (unsigned short*)p; p += (size_t)HID * KDIM * 2;      // 128 KB
    unsigned short* C2W  = (unsigned short*)p; p += (size_t)16 * KDIM * 2;       // 16 KB
    float* zbuf          = (float*)p;          p += (size_t)N_NODES * 16 * 4;    // 6.4 MB
    int*   row_start     = (int*)p;            p += (size_t)(N_NODES + 1) * 4;
    int*   bcnt          = (int*)p;            p += (size_t)NB * 16 * 4;         // 50 KB
    int*   bbase         = (int*)p;            p += (size_t)NB * 4;

    // bucket buffer aliases hA (dead until gemm_xw): 782*4096*4 = 12.8 MB < 25.6 MB
    unsigned* bbuf = (unsigned*)hA;

    const int nblk_gemm = (N_NODES + 63) / 64;         // 1563
    const int nblk_edge = N_EDGES / 256;               // 6250
    const int nblk_spmm = (N_NODES + 3) / 4;           // 25000

    hipMemsetAsync(bcnt, 0, (size_t)NB * 16 * 4, stream);
    bin_kernel<<<nblk_edge, 256, 0, stream>>>(ei, bcnt, bbuf);
    bscan_kernel<<<1, 1024, 0, stream>>>(bcnt, bbase);
    place_kernel<<<NB, 256, 0, stream>>>(bbuf, bcnt, bbase, row_start, col_sorted);
    repack_cheb<<<HID * KDIM / 256, 256, 0, stream>>>(cheb, Bmat);
    repack_w<<<HID * KDIM / 256, 256, 0, stream>>>(W_in, Wmat);
    repack_c2w<<<16 * KDIM / 256, 256, 0, stream>>>(cheb, W_out, C2W);

    gemm_xw<<<nblk_gemm, 256, 0, stream>>>(x, Wmat, hA);
    spmm_gather<<<nblk_spmm, 256, 0, stream>>>(row_start, col_sorted, hA, hB);

    cheb_gemm<<<nblk_gemm, 256, 0, stream>>>(hB, Bmat, hA);                    // layer 0
    spmm_gather<<<nblk_spmm, 256, 0, stream>>>(row_start, col_sorted, hA, hB);

    cheb16_gemm<<<nblk_gemm, 256, 0, stream>>>(hB, C2W, zbuf);                 // layer 1 + W_out
    spmm_out<<<nblk_spmm, 256, 0, stream>>>(row_start, col_sorted, zbuf, out); // spmm + lsm
}